// Round 8
// baseline (803.410 us; speedup 1.0000x reference)
//
#include <hip/hip_runtime.h>
#include <hip/hip_bf16.h>
#include <math.h>

#define B_   2
#define Q_   2048
#define M_   2048
#define H_   16
#define D_   64
#define HID_ 1024
#define KL_  4096
#define RT_  64      // q rows per attention block
#define WT_  128     // k cols per attention tile
#define EPAD 256     // e-table tail padding (band reads past KL land here)
#define LSCL 0.022542110013890053f   // log2(e)/64 — logits kept in log2 units

typedef short short8 __attribute__((ext_vector_type(8)));
typedef short short4v __attribute__((ext_vector_type(4)));
typedef float f32x4 __attribute__((ext_vector_type(4)));

__device__ __forceinline__ void async_copy16(const void* g, void* l) {
  __builtin_amdgcn_global_load_lds((const __attribute__((address_space(1))) unsigned int*)g,
                                   (__attribute__((address_space(3))) unsigned int*)l,
                                   16, 0, 0);
}

// read input element i as float, md=1 -> fp32 buffer, md=0 -> bf16 buffer
__device__ __forceinline__ float ldin(const void* p, size_t i, int md) {
  return md ? ((const float*)p)[i] : __bfloat162float(((const __hip_bfloat16*)p)[i]);
}

__device__ __forceinline__ short bfbits(float v) {
  __hip_bfloat16 t = __float2bfloat16(v);
  return *(short*)&t;
}

// fast 2^x: lowers to v_exp_f32 (HW computes 2^x natively)
__device__ __forceinline__ float fexp2(float x) { return exp2f(x); }

// ---------------- dtype detector: writes 1 if inputs are fp32, else 0 ----------------
__global__ __launch_bounds__(256) void detect_kernel(const unsigned int* __restrict__ q,
                                                     int* __restrict__ flag) {
  __shared__ int cnt;
  if (threadIdx.x == 0) cnt = 0;
  __syncthreads();
  int ins = 0;
#pragma unroll
  for (int i = 0; i < 4; i++) {
    unsigned int u = q[threadIdx.x * 4 + i];
    int e0 = (int)((u >> 7) & 0xffu);
    int e1 = (int)((u >> 23) & 0xffu);
    if (e0 == 0xff || e0 < 102 || e0 > 140) ins++;
    if (e1 == 0xff || e1 < 102 || e1 > 140) ins++;
  }
  atomicAdd(&cnt, ins);
  __syncthreads();
  if (threadIdx.x == 0) *flag = (cnt > 512) ? 1 : 0;
}

// ---------------- fused weight transposes: wt[n][k] = src[k][n], 5 x 1024x1024 ----------------
__global__ __launch_bounds__(256) void wt5_kernel(
    const void* __restrict__ s0, const void* __restrict__ s1, const void* __restrict__ s2,
    const void* __restrict__ s3, const void* __restrict__ s4,
    __hip_bfloat16* __restrict__ d0, __hip_bfloat16* __restrict__ d1,
    __hip_bfloat16* __restrict__ d2, __hip_bfloat16* __restrict__ d3,
    __hip_bfloat16* __restrict__ d4, const int* __restrict__ mode) {
  const int md = *mode;
  const void* src; __hip_bfloat16* dst;
  switch (blockIdx.z) {
    case 0: src = s0; dst = d0; break;
    case 1: src = s1; dst = d1; break;
    case 2: src = s2; dst = d2; break;
    case 3: src = s3; dst = d3; break;
    default: src = s4; dst = d4; break;
  }
  const int r0 = blockIdx.x * 64, c0 = blockIdx.y * 64;
  __shared__ __hip_bfloat16 t[64][65];
  const int tid = threadIdx.x;
  const int col = tid & 63, r4 = tid >> 6;
#pragma unroll
  for (int i = 0; i < 16; i++)
    t[r4 + i * 4][col] = __float2bfloat16(ldin(src, (size_t)(r0 + r4 + i * 4) * HID_ + c0 + col, md));
  __syncthreads();
#pragma unroll
  for (int i = 0; i < 16; i++)
    dst[(size_t)(c0 + r4 + i * 4) * HID_ + r0 + col] = t[col][r4 + i * 4];
}

// ---------------- V transpose: vpt[b][h][d][j] = vp[b*K+j][h*64+d] ----------------
__global__ __launch_bounds__(256) void vpt_kernel(const __hip_bfloat16* __restrict__ vp,
                                                  __hip_bfloat16* __restrict__ vpt) {
  const int jt = blockIdx.x * 64;
  const int bh = blockIdx.y;
  const int b = bh / H_, h = bh % H_;
  __shared__ __hip_bfloat16 t[64][65];
  const int tid = threadIdx.x;
  const int col = tid & 63, r4 = tid >> 6;
#pragma unroll
  for (int i = 0; i < 16; i++) {
    int j = r4 + i * 4;
    t[j][col] = vp[((size_t)b * KL_ + jt + j) * HID_ + h * D_ + col];
  }
  __syncthreads();
#pragma unroll
  for (int i = 0; i < 16; i++) {
    int d = r4 + i * 4;
    vpt[(((size_t)b * H_ + h) * D_ + d) * KL_ + jt + col] = t[col][d];
  }
}

// ---------------- LayerNorm over concat(memory, query) rows ----------------
__global__ __launch_bounds__(256) void ln_kv_kernel(
    const void* __restrict__ mem, const void* __restrict__ qry,
    const void* __restrict__ gamma, const void* __restrict__ beta,
    __hip_bfloat16* __restrict__ out, const int* __restrict__ mode) {
  const int md = *mode;
  const int row = blockIdx.x;  // 0..B*KL-1
  const int b = row / KL_, j = row % KL_;
  const void* src;
  size_t base;
  if (j < M_) { src = mem; base = ((size_t)b * M_ + j) * HID_; }
  else        { src = qry; base = ((size_t)b * Q_ + (j - M_)) * HID_; }
  const int tid = threadIdx.x;
  float x[4];
  float s = 0.f, ss = 0.f;
#pragma unroll
  for (int i = 0; i < 4; i++) {
    x[i] = ldin(src, base + i * 256 + tid, md);
    s += x[i]; ss += x[i] * x[i];
  }
#pragma unroll
  for (int o = 32; o > 0; o >>= 1) { s += __shfl_down(s, o); ss += __shfl_down(ss, o); }
  __shared__ float red[8];
  if ((tid & 63) == 0) { red[(tid >> 6) * 2] = s; red[(tid >> 6) * 2 + 1] = ss; }
  __syncthreads();
  float ts = 0.f, tss = 0.f;
#pragma unroll
  for (int i = 0; i < 4; i++) { ts += red[i * 2]; tss += red[i * 2 + 1]; }
  const float mu = ts * (1.f / 1024.f);
  const float var = tss * (1.f / 1024.f) - mu * mu;
  const float rs = rsqrtf(var + 1e-3f);
  __hip_bfloat16* dst = out + (size_t)row * HID_;
#pragma unroll
  for (int i = 0; i < 4; i++) {
    int c = i * 256 + tid;
    dst[c] = __float2bfloat16((x[i] - mu) * rs * ldin(gamma, c, md) + ldin(beta, c, md));
  }
}

__global__ __launch_bounds__(256) void ln_q_kernel(
    const void* __restrict__ qry,
    const void* __restrict__ gamma, const void* __restrict__ beta,
    __hip_bfloat16* __restrict__ out, const int* __restrict__ mode) {
  const int md = *mode;
  const int row = blockIdx.x;  // 0..B*Q-1
  const size_t base = (size_t)row * HID_;
  const int tid = threadIdx.x;
  float x[4];
  float s = 0.f, ss = 0.f;
#pragma unroll
  for (int i = 0; i < 4; i++) {
    x[i] = ldin(qry, base + i * 256 + tid, md);
    s += x[i]; ss += x[i] * x[i];
  }
#pragma unroll
  for (int o = 32; o > 0; o >>= 1) { s += __shfl_down(s, o); ss += __shfl_down(ss, o); }
  __shared__ float red[8];
  if ((tid & 63) == 0) { red[(tid >> 6) * 2] = s; red[(tid >> 6) * 2 + 1] = ss; }
  __syncthreads();
  float ts = 0.f, tss = 0.f;
#pragma unroll
  for (int i = 0; i < 4; i++) { ts += red[i * 2]; tss += red[i * 2 + 1]; }
  const float mu = ts * (1.f / 1024.f);
  const float var = tss * (1.f / 1024.f) - mu * mu;
  const float rs = rsqrtf(var + 1e-3f);
  __hip_bfloat16* dst = out + (size_t)row * HID_;
#pragma unroll
  for (int i = 0; i < 4; i++) {
    int c = i * 256 + tid;
    dst[c] = __float2bfloat16((x[i] - mu) * rs * ldin(gamma, c, md) + ldin(beta, c, md));
  }
}

// ---------------- sinusoidal position embedding, positions K-1..0 ----------------
__global__ __launch_bounds__(256) void posemb_kernel(__hip_bfloat16* __restrict__ pe) {
  const int p = blockIdx.x;
  const float pos = (float)(KL_ - 1 - p);
  const int tid = threadIdx.x;
#pragma unroll
  for (int i = 0; i < 4; i++) {
    int c = tid * 4 + i;
    int f = (c < 512) ? c : c - 512;
    float invf = fexp2(-(float)f * (13.287712379549449f / 512.0f));
    float a = pos * invf;
    float v = (c < 512) ? __sinf(a) : __cosf(a);
    pe[(size_t)p * HID_ + c] = __float2bfloat16(v);
  }
}

// ---------------- GEMM core: C = A @ BT^T (both bf16, K=1024), 128x128 tile ----------------
template <int WRITE_MODE_SWITCH>
__device__ __forceinline__ void gemm_body(const __hip_bfloat16* __restrict__ A,
                                          const __hip_bfloat16* __restrict__ BT,
                                          void* __restrict__ C, int md, float scl) {
  __shared__ __attribute__((aligned(16))) __hip_bfloat16 sA[128 * 32];
  __shared__ __attribute__((aligned(16))) __hip_bfloat16 sB[128 * 32];
  const int tid = threadIdx.x;
  const int lane = tid & 63;
  const int w = tid >> 6;
  const int quad = lane >> 4, l16 = lane & 15;
  const int m0 = blockIdx.x * 128;
  const int n0 = blockIdx.y * 128;
  const int wm = (w >> 1) * 64, wn = (w & 1) * 64;
  const f32x4 fz = {0.f, 0.f, 0.f, 0.f};

  f32x4 acc[4][4];
#pragma unroll
  for (int i = 0; i < 4; i++)
#pragma unroll
    for (int j = 0; j < 4; j++) acc[i][j] = fz;

  for (int kk = 0; kk < HID_ / 32; kk++) {
    const int k0 = kk * 32;
    __syncthreads();
#pragma unroll
    for (int t = 0; t < 2; t++) {
      int c = (w * 2 + t) * 64 + lane;
      int row = c >> 2;
      int cid = (c & 3) ^ (row & 3);
      async_copy16(A + (size_t)(m0 + row) * HID_ + k0 + cid * 8, (char*)sA + c * 16);
      async_copy16(BT + (size_t)(n0 + row) * HID_ + k0 + cid * 8, (char*)sB + c * 16);
    }
    __syncthreads();
    short8 af[4], bf[4];
#pragma unroll
    for (int mt = 0; mt < 4; mt++) {
      int r = wm + mt * 16 + l16;
      af[mt] = *(const short8*)((const char*)sA + r * 64 + ((quad ^ (r & 3)) * 16));
    }
#pragma unroll
    for (int nt = 0; nt < 4; nt++) {
      int r = wn + nt * 16 + l16;
      bf[nt] = *(const short8*)((const char*)sB + r * 64 + ((quad ^ (r & 3)) * 16));
    }
#pragma unroll
    for (int mt = 0; mt < 4; mt++)
#pragma unroll
      for (int nt = 0; nt < 4; nt++)
        acc[mt][nt] = __builtin_amdgcn_mfma_f32_16x16x32_bf16(af[mt], bf[nt], acc[mt][nt], 0, 0, 0);
  }
#pragma unroll
  for (int mt = 0; mt < 4; mt++)
#pragma unroll
    for (int nt = 0; nt < 4; nt++)
#pragma unroll
      for (int rg = 0; rg < 4; rg++) {
        int r = m0 + wm + mt * 16 + quad * 4 + rg;
        int cc = n0 + wn + nt * 16 + l16;
        size_t idx = (size_t)r * HID_ + cc;
        if (WRITE_MODE_SWITCH && md) ((float*)C)[idx] = acc[mt][nt][rg];
        else ((__hip_bfloat16*)C)[idx] = __float2bfloat16(acc[mt][nt][rg] * scl);
      }
}

__global__ __launch_bounds__(256) void gemm_bt128(const __hip_bfloat16* __restrict__ A,
                                                  const __hip_bfloat16* __restrict__ BT,
                                                  __hip_bfloat16* __restrict__ C, float scl) {
  gemm_body<0>(A, BT, (void*)C, 0, scl);
}

__global__ __launch_bounds__(256) void gemm_out(const __hip_bfloat16* __restrict__ A,
                                                const __hip_bfloat16* __restrict__ BT,
                                                void* __restrict__ C,
                                                const int* __restrict__ mode) {
  gemm_body<1>(A, BT, C, *mode, 1.0f);
}

// ---------------- bias dots (pre-scaled by log2e/64) ----------------
__global__ __launch_bounds__(256) void cbias_kernel(const __hip_bfloat16* __restrict__ kp,
                                                    const void* __restrict__ rwb,
                                                    float* __restrict__ cb,
                                                    const int* __restrict__ mode) {
  const int md = *mode;
  const int idx = blockIdx.x * 256 + threadIdx.x;  // B*H*KL
  const int j = idx % KL_;
  const int h = (idx / KL_) % H_;
  const int b = idx / (KL_ * H_);
  const __hip_bfloat16* kr = kp + ((size_t)b * KL_ + j) * HID_ + h * D_;
  float s = 0.f;
#pragma unroll
  for (int t = 0; t < 8; t++) {
    short8 v = *(const short8*)(kr + t * 8);
#pragma unroll
    for (int u = 0; u < 8; u++) {
      short sb = v[u];
      s += __bfloat162float(*(__hip_bfloat16*)&sb) * ldin(rwb, h * D_ + t * 8 + u, md);
    }
  }
  cb[idx] = s * LSCL;
}

__global__ __launch_bounds__(256) void ebias_kernel(const __hip_bfloat16* __restrict__ relp,
                                                    const void* __restrict__ rrb,
                                                    float* __restrict__ eb,
                                                    const int* __restrict__ mode) {
  const int md = *mode;
  const int idx = blockIdx.x * 256 + threadIdx.x;  // H*(KL+EPAD)
  const int p = idx % (KL_ + EPAD);
  const int h = idx / (KL_ + EPAD);
  const int pc = p < KL_ ? p : KL_ - 1;            // pad rows: finite junk (masked downstream)
  const __hip_bfloat16* rr = relp + (size_t)pc * HID_ + h * D_;
  float s = 0.f;
#pragma unroll
  for (int t = 0; t < 8; t++) {
    short8 v = *(const short8*)(rr + t * 8);
#pragma unroll
    for (int u = 0; u < 8; u++) {
      short sb = v[u];
      s += __bfloat162float(*(__hip_bfloat16*)&sb) * ldin(rrb, h * D_ + t * 8 + u, md);
    }
  }
  eb[idx] = s * LSCL;
}

// ---------------- fused relative attention ----------------
// grid 1024 flat (XCD-remapped), block 256 (4 waves). Logits in log2 units. LDS = 51 KB
// (K tile + V^T tile + sTP) -> 3 blocks/CU. rel A-frags read DIRECT from global (L2-hot
// via XCD swizzle; loads issued before S-MFMAs so they fly behind compute). 2 barriers/tile.
__global__ __launch_bounds__(256, 3) void attn_kernel(
    const __hip_bfloat16* __restrict__ qp, const __hip_bfloat16* __restrict__ kp,
    const __hip_bfloat16* __restrict__ vpt, const __hip_bfloat16* __restrict__ relp,
    const float* __restrict__ cb, const float* __restrict__ eb,
    const void* __restrict__ spanv, __hip_bfloat16* __restrict__ attn_out,
    const int* __restrict__ mode) {
  const int md = *mode;
  const int bid = blockIdx.x;
  const int bh = (bid & 7) + 8 * (bid >> 8);
  const int i0 = ((bid >> 3) & 31) * RT_;
  const int b = bh >> 4, h = bh & 15;

  const int tid = threadIdx.x;
  const int lane = tid & 63;
  const int w = tid >> 6;
  const int quad = lane >> 4, l16 = lane & 15;
  const int di = w * 16 + l16;        // this thread's softmax row (block-local)
  const int iRow = i0 + di;
  const f32x4 fz = {0.f, 0.f, 0.f, 0.f};

  __shared__ __attribute__((aligned(16))) __hip_bfloat16 sk[128 * 64];    // 16 KB K tile (q staged here first)
  __shared__ __attribute__((aligned(16))) __hip_bfloat16 svt[64 * 128];   // 16 KB V^T tile
  __shared__ __attribute__((aligned(16))) short sTP[64 * 152];            // 19 KB T-band/P rows

  const int rb = di * 304;            // private row base (bytes), 16B-aligned

  const __hip_bfloat16* kbase = kp + (size_t)b * KL_ * HID_ + h * D_;
  const __hip_bfloat16* vtb = vpt + ((size_t)(b * H_ + h)) * D_ * KL_;
  const __hip_bfloat16* relh = relp + h * D_;
  const float* cbb = cb + (size_t)(b * H_ + h) * KL_;
  const float* ebb = eb + (size_t)h * (KL_ + EPAD);
  const float sv = ldin(spanv, h, md);
  const float svQ = sv * (float)Q_;
  const int pb0 = Q_ - RT_ - i0;
  const int wof = (3 - w) * 16;       // this wave's T-band p-window offset
  const int ntiles = ((M_ + i0 + RT_ - 1) >> 7) + 1;

  // ---- stage q once via sk, read own-row B-fragments ----
  {
    const __hip_bfloat16* qb = qp + ((size_t)(b * Q_ + i0)) * HID_ + h * D_;
#pragma unroll
    for (int t = 0; t < 2; t++) {
      int c = (w * 2 + t) * 64 + lane;
      int row = c >> 3;
      int cid = (c & 7) ^ (row & 7);
      async_copy16(qb + (size_t)row * HID_ + cid * 8, (char*)sk + c * 16);
    }
  }
  __syncthreads();
  short8 qf[2];
#pragma unroll
  for (int ks = 0; ks < 2; ks++)
    qf[ks] = *(const short8*)((const char*)sk + di * 128 + (((ks * 4 + quad) ^ (di & 7)) * 16));

  float mrow = -3e38f, lrow = 0.f, dfrow = 0.f;
  f32x4 oacc[4];
#pragma unroll
  for (int dt = 0; dt < 4; dt++) oacc[dt] = fz;

  for (int kt = 0; kt < ntiles; kt++) {
    const int j0 = kt * WT_;
    const int pbase = pb0 + j0;

    __syncthreads();  // A: prior tile's sk/svt/q-frag consumers done
    // ---- DMA staging: K (4), V^T (4) ----
#pragma unroll
    for (int t = 0; t < 4; t++) {
      int c = (w * 4 + t) * 64 + lane;
      int row = c >> 3;
      int cid = (c & 7) ^ (row & 7);
      async_copy16(kbase + (size_t)(j0 + row) * HID_ + cid * 8, (char*)sk + c * 16);
    }
#pragma unroll
    for (int t = 0; t < 4; t++) {
      int c = (w * 4 + t) * 64 + lane;
      int row = c >> 4;
      int cid = (c & 15) ^ (row & 15);
      async_copy16(vtb + (size_t)row * KL_ + j0 + cid * 8, (char*)svt + c * 16);
    }
    __syncthreads();  // B: DMA drained (32 KB)

    // ---- rel A-frags: direct global loads, issued NOW, consumed after S ----
    short8 rrf[9][2];
#pragma unroll
    for (int mt = 0; mt < 9; mt++) {
      int p = pbase + wof + mt * 16 + l16;
      p = p < KL_ ? p : KL_ - 1;   // clamped rows feed only masked cols
      const __hip_bfloat16* rr = relh + (size_t)p * HID_;
#pragma unroll
      for (int ks = 0; ks < 2; ks++)
        rrf[mt][ks] = *(const short8*)(rr + ks * 32 + quad * 8);
    }

    // ---- S^T[j][i] = K . Q^T (rel loads in flight behind this) ----
    f32x4 S[8];
#pragma unroll
    for (int mt = 0; mt < 8; mt++) S[mt] = fz;
#pragma unroll
    for (int mt = 0; mt < 8; mt++) {
      int r = mt * 16 + l16;
#pragma unroll
      for (int ks = 0; ks < 2; ks++) {
        short8 af = *(const short8*)((const char*)sk + r * 128 + (((ks * 4 + quad) ^ (r & 7)) * 16));
        S[mt] = __builtin_amdgcn_mfma_f32_16x16x32_bf16(af, qf[ks], S[mt], 0, 0, 0);
      }
    }

    // ---- T band (wave's 144-col window), +e, store into own sTP row ----
#pragma unroll
    for (int mt = 0; mt < 9; mt++) {
      f32x4 T = fz;
#pragma unroll
      for (int ks = 0; ks < 2; ks++)
        T = __builtin_amdgcn_mfma_f32_16x16x32_bf16(rrf[mt][ks], qf[ks], T, 0, 0, 0);
      const int lo = mt * 16 + quad * 4;              // local band offset [0,144)
      f32x4 e4 = *(const f32x4*)(ebb + pbase + wof + lo);
      short4v pk;
#pragma unroll
      for (int rg = 0; rg < 4; rg++) pk[rg] = bfbits(T[rg] + e4[rg]);
      *(short4v*)((char*)sTP + rb + lo * 2) = pk;
    }

    // ---- gather with per-row shift (own row, in-order DS) ----
#pragma unroll
    for (int mt = 0; mt < 8; mt++)
#pragma unroll
      for (int rg = 0; rg < 4; rg++) {
        int tcl = 15 - l16 + mt * 16 + quad * 4 + rg;
        S[mt][rg] += __bfloat162float(*(const __hip_bfloat16*)((const char*)sTP + rb + tcl * 2));
      }

    // ---- logits (log2 units), causal mask only on tiles that can need it ----
    const bool causalT = (j0 + WT_ - 1 - i0) > M_;
    float mnew = mrow;
#pragma unroll
    for (int mt = 0; mt < 8; mt++) {
      f32x4 cb4 = *(const f32x4*)(cbb + j0 + mt * 16 + quad * 4);
#pragma unroll
      for (int rg = 0; rg < 4; rg++) {
        float v = S[mt][rg] + cb4[rg];
        if (causalT) {
          int j = j0 + mt * 16 + quad * 4 + rg;
          if (j - iRow > M_) v = -1e30f;
        }
        S[mt][rg] = v;
        mnew = fmaxf(mnew, v);
      }
    }
    mnew = fmaxf(mnew, __shfl_xor(mnew, 16));
    mnew = fmaxf(mnew, __shfl_xor(mnew, 32));
    const float alpha = fexp2(mrow - mnew);
    mrow = mnew;
    lrow *= alpha; dfrow *= alpha;
    float aR[4];
#pragma unroll
    for (int rg = 0; rg < 4; rg++) aR[rg] = __shfl(alpha, quad * 4 + rg);
#pragma unroll
    for (int dt = 0; dt < 4; dt++)
#pragma unroll
      for (int rg = 0; rg < 4; rg++) oacc[dt][rg] *= aR[rg];

    // ---- P = exp2(S-m); span deficit only on tiles overlapping the ramp ----
    const bool maskT = (j0 + WT_ > M_) && ((float)j0 < (float)M_ + 33.f - svQ);
#pragma unroll
    for (int mt = 0; mt < 8; mt++) {
      short4v pk;
#pragma unroll
      for (int rg = 0; rg < 4; rg++) {
        float pv = fexp2(S[mt][rg] - mrow);
        lrow += pv;
        float pm = pv;
        if (maskT) {
          int j = j0 + mt * 16 + quad * 4 + rg;
          if (j >= M_) {
            float t0 = (float)(j - M_) + svQ;
            float mk = fminf(fmaxf(t0 * (1.0f / 33.0f), 0.f), 1.f);
            pm = pv * mk;
            dfrow += pv - pm;
          }
        }
        pk[rg] = bfbits(pm);
      }
      *(short4v*)((char*)sTP + rb + (mt * 16 + quad * 4) * 2) = pk;
    }

    // ---- PV: A = P (own rows, b128 from sTP), B = V^T rows from svt ----
#pragma unroll
    for (int ks = 0; ks < 4; ks++) {
      short8 af = *(const short8*)((const char*)sTP + rb + ks * 64 + quad * 16);
#pragma unroll
      for (int dt = 0; dt < 4; dt++) {
        int r = dt * 16 + l16;
        short8 bfv = *(const short8*)((const char*)svt + r * 256 + (((ks * 4 + quad) ^ (r & 15)) * 16));
        oacc[dt] = __builtin_amdgcn_mfma_f32_16x16x32_bf16(af, bfv, oacc[dt], 0, 0, 0);
      }
    }
  }

  // ---- epilogue: lm = lr - deficit ----
  lrow += __shfl_xor(lrow, 16);  lrow += __shfl_xor(lrow, 32);
  dfrow += __shfl_xor(dfrow, 16); dfrow += __shfl_xor(dfrow, 32);
  float lr4[4], df4[4];
#pragma unroll
  for (int rg = 0; rg < 4; rg++) {
    lr4[rg] = __shfl(lrow, quad * 4 + rg);
    df4[rg] = __shfl(dfrow, quad * 4 + rg);
  }
#pragma unroll
  for (int dt = 0; dt < 4; dt++)
#pragma unroll
    for (int rg = 0; rg < 4; rg++) {
      int i = i0 + w * 16 + quad * 4 + rg;
      float denom = (lr4[rg] - df4[rg]) + 1e-8f * lr4[rg];
      float ov = oacc[dt][rg] / denom;
      attn_out[((size_t)(b * Q_ + i)) * HID_ + h * D_ + dt * 16 + l16] = __float2bfloat16(ov);
    }
}

// ---------------- launcher ----------------
extern "C" void kernel_launch(void* const* d_in, const int* in_sizes, int n_in,
                              void* d_out, int out_size, void* d_ws, size_t ws_size,
                              hipStream_t stream) {
  const void* query  = d_in[0];
  const void* memory = d_in[1];
  const void* Wq = d_in[2];
  const void* Wk = d_in[3];
  const void* Wv = d_in[4];
  const void* Wo = d_in[5];
  const void* Wr = d_in[6];
  const void* gmem = d_in[7];
  const void* bmem = d_in[8];
  const void* gq = d_in[9];
  const void* bq = d_in[10];
  const void* rwb = d_in[11];
  const void* rrb = d_in[12];
  const void* spanv = d_in[13];

  char* ws = (char*)d_ws;
  size_t off = 0;
  auto alloc = [&](size_t bytes) -> char* {
    char* p = ws + off;
    off += (bytes + 255) & ~(size_t)255;
    return p;
  };
  int* flag = (int*)alloc(256);
  const size_t SZ_W = (size_t)HID_ * HID_ * 2;
  __hip_bfloat16* wqT = (__hip_bfloat16*)alloc(SZ_W);
  __hip_bfloat16* wkT = (__hip_bfloat16*)alloc(SZ_W);
  __hip_bfloat16* wvT = (__hip_bfloat16*)alloc(SZ_W);
  __hip_bfloat16* wrT = (__hip_bfloat16*)alloc(SZ_W);
  __hip_bfloat16* woT = (__hip_bfloat16*)alloc(SZ_W);
  __hip_bfloat16* kvln = (__hip_bfloat16*)alloc((size_t)B_ * KL_ * HID_ * 2);
  __hip_bfloat16* qln  = (__hip_bfloat16*)alloc((size_t)B_ * Q_ * HID_ * 2);
  __hip_bfloat16* pe   = (__hip_bfloat16*)alloc((size_t)KL_ * HID_ * 2);
  __hip_bfloat16* qpb  = (__hip_bfloat16*)alloc((size_t)B_ * Q_ * HID_ * 2);
  __hip_bfloat16* kpb  = (__hip_bfloat16*)alloc((size_t)B_ * KL_ * HID_ * 2);
  __hip_bfloat16* vpb  = (__hip_bfloat16*)alloc((size_t)B_ * KL_ * HID_ * 2);
  __hip_bfloat16* relp = (__hip_bfloat16*)alloc((size_t)KL_ * HID_ * 2);
  __hip_bfloat16* aout = (__hip_bfloat16*)alloc((size_t)B_ * Q_ * HID_ * 2);
  float* cbf = (float*)alloc((size_t)B_ * H_ * KL_ * 4);
  float* ebf = (float*)alloc((size_t)H_ * (KL_ + EPAD) * 4);
  __hip_bfloat16* vptb = kvln;  // alias: kvln dead after the k/v projection GEMMs

  dim3 tb(256);
  detect_kernel<<<dim3(1), tb, 0, stream>>>((const unsigned int*)query, flag);

  wt5_kernel<<<dim3(16, 16, 5), tb, 0, stream>>>(Wq, Wk, Wv, Wr, Wo,
                                                 wqT, wkT, wvT, wrT, woT, flag);

  ln_kv_kernel<<<dim3(B_ * KL_), tb, 0, stream>>>(memory, query, gmem, bmem, kvln, flag);
  ln_q_kernel<<<dim3(B_ * Q_), tb, 0, stream>>>(query, gq, bq, qln, flag);
  posemb_kernel<<<dim3(KL_), tb, 0, stream>>>(pe);

  gemm_bt128<<<dim3(B_ * Q_ / 128, HID_ / 128), tb, 0, stream>>>(qln, wqT, qpb, LSCL);
  gemm_bt128<<<dim3(B_ * KL_ / 128, HID_ / 128), tb, 0, stream>>>(kvln, wkT, kpb, 1.0f);
  gemm_bt128<<<dim3(B_ * KL_ / 128, HID_ / 128), tb, 0, stream>>>(kvln, wvT, vpb, 1.0f);
  gemm_bt128<<<dim3(KL_ / 128, HID_ / 128), tb, 0, stream>>>(pe, wrT, relp, 1.0f);

  vpt_kernel<<<dim3(KL_ / 64, B_ * H_), tb, 0, stream>>>(vpb, vptb);
  cbias_kernel<<<dim3(B_ * H_ * KL_ / 256), tb, 0, stream>>>(kpb, rwb, cbf, flag);
  ebias_kernel<<<dim3(H_ * (KL_ + EPAD) / 256), tb, 0, stream>>>(relp, rrb, ebf, flag);

  attn_kernel<<<dim3((Q_ / RT_) * H_ * B_), tb, 0, stream>>>(qpb, kpb, vptb, relp, cbf, ebf, spanv, aout, flag);

  gemm_out<<<dim3(B_ * Q_ / 128, HID_ / 128), tb, 0, stream>>>(aout, woT, d_out, flag);

  (void)in_sizes; (void)n_in; (void)out_size; (void)ws_size;
}

// Round 9
// 751.146 us; speedup vs baseline: 1.0696x; 1.0696x over previous
//
#include <hip/hip_runtime.h>
#include <hip/hip_bf16.h>
#include <math.h>

#define B_   2
#define Q_   2048
#define M_   2048
#define H_   16
#define D_   64
#define HID_ 1024
#define KL_  4096
#define RT_  64      // q rows per attention block
#define WT_  128     // k cols per attention tile
#define EPAD 256     // e-table tail padding (band reads past KL land here)
#define LSCL 0.022542110013890053f   // log2(e)/64 — logits kept in log2 units

typedef short short8 __attribute__((ext_vector_type(8)));
typedef short short4v __attribute__((ext_vector_type(4)));
typedef float f32x4 __attribute__((ext_vector_type(4)));

__device__ __forceinline__ void async_copy16(const void* g, void* l) {
  __builtin_amdgcn_global_load_lds((const __attribute__((address_space(1))) unsigned int*)g,
                                   (__attribute__((address_space(3))) unsigned int*)l,
                                   16, 0, 0);
}

// read input element i as float, md=1 -> fp32 buffer, md=0 -> bf16 buffer
__device__ __forceinline__ float ldin(const void* p, size_t i, int md) {
  return md ? ((const float*)p)[i] : __bfloat162float(((const __hip_bfloat16*)p)[i]);
}

__device__ __forceinline__ short bfbits(float v) {
  __hip_bfloat16 t = __float2bfloat16(v);
  return *(short*)&t;
}

// fast 2^x: lowers to v_exp_f32 (HW computes 2^x natively)
__device__ __forceinline__ float fexp2(float x) { return exp2f(x); }

// ---------------- dtype detector: writes 1 if inputs are fp32, else 0 ----------------
__global__ __launch_bounds__(256) void detect_kernel(const unsigned int* __restrict__ q,
                                                     int* __restrict__ flag) {
  __shared__ int cnt;
  if (threadIdx.x == 0) cnt = 0;
  __syncthreads();
  int ins = 0;
#pragma unroll
  for (int i = 0; i < 4; i++) {
    unsigned int u = q[threadIdx.x * 4 + i];
    int e0 = (int)((u >> 7) & 0xffu);
    int e1 = (int)((u >> 23) & 0xffu);
    if (e0 == 0xff || e0 < 102 || e0 > 140) ins++;
    if (e1 == 0xff || e1 < 102 || e1 > 140) ins++;
  }
  atomicAdd(&cnt, ins);
  __syncthreads();
  if (threadIdx.x == 0) *flag = (cnt > 512) ? 1 : 0;
}

// ---------------- fused weight transposes: wt[n][k] = src[k][n], 5 x 1024x1024 ----------------
__global__ __launch_bounds__(256) void wt5_kernel(
    const void* __restrict__ s0, const void* __restrict__ s1, const void* __restrict__ s2,
    const void* __restrict__ s3, const void* __restrict__ s4,
    __hip_bfloat16* __restrict__ d0, __hip_bfloat16* __restrict__ d1,
    __hip_bfloat16* __restrict__ d2, __hip_bfloat16* __restrict__ d3,
    __hip_bfloat16* __restrict__ d4, const int* __restrict__ mode) {
  const int md = *mode;
  const void* src; __hip_bfloat16* dst;
  switch (blockIdx.z) {
    case 0: src = s0; dst = d0; break;
    case 1: src = s1; dst = d1; break;
    case 2: src = s2; dst = d2; break;
    case 3: src = s3; dst = d3; break;
    default: src = s4; dst = d4; break;
  }
  const int r0 = blockIdx.x * 64, c0 = blockIdx.y * 64;
  __shared__ __hip_bfloat16 t[64][65];
  const int tid = threadIdx.x;
  const int col = tid & 63, r4 = tid >> 6;
#pragma unroll
  for (int i = 0; i < 16; i++)
    t[r4 + i * 4][col] = __float2bfloat16(ldin(src, (size_t)(r0 + r4 + i * 4) * HID_ + c0 + col, md));
  __syncthreads();
#pragma unroll
  for (int i = 0; i < 16; i++)
    dst[(size_t)(c0 + r4 + i * 4) * HID_ + r0 + col] = t[col][r4 + i * 4];
}

// ---------------- V transpose: vpt[b][h][d][j] = vp[b*K+j][h*64+d] ----------------
__global__ __launch_bounds__(256) void vpt_kernel(const __hip_bfloat16* __restrict__ vp,
                                                  __hip_bfloat16* __restrict__ vpt) {
  const int jt = blockIdx.x * 64;
  const int bh = blockIdx.y;
  const int b = bh / H_, h = bh % H_;
  __shared__ __hip_bfloat16 t[64][65];
  const int tid = threadIdx.x;
  const int col = tid & 63, r4 = tid >> 6;
#pragma unroll
  for (int i = 0; i < 16; i++) {
    int j = r4 + i * 4;
    t[j][col] = vp[((size_t)b * KL_ + jt + j) * HID_ + h * D_ + col];
  }
  __syncthreads();
#pragma unroll
  for (int i = 0; i < 16; i++) {
    int d = r4 + i * 4;
    vpt[(((size_t)b * H_ + h) * D_ + d) * KL_ + jt + col] = t[col][d];
  }
}

// ---------------- LayerNorm over concat(memory, query) rows ----------------
__global__ __launch_bounds__(256) void ln_kv_kernel(
    const void* __restrict__ mem, const void* __restrict__ qry,
    const void* __restrict__ gamma, const void* __restrict__ beta,
    __hip_bfloat16* __restrict__ out, const int* __restrict__ mode) {
  const int md = *mode;
  const int row = blockIdx.x;  // 0..B*KL-1
  const int b = row / KL_, j = row % KL_;
  const void* src;
  size_t base;
  if (j < M_) { src = mem; base = ((size_t)b * M_ + j) * HID_; }
  else        { src = qry; base = ((size_t)b * Q_ + (j - M_)) * HID_; }
  const int tid = threadIdx.x;
  float x[4];
  float s = 0.f, ss = 0.f;
#pragma unroll
  for (int i = 0; i < 4; i++) {
    x[i] = ldin(src, base + i * 256 + tid, md);
    s += x[i]; ss += x[i] * x[i];
  }
#pragma unroll
  for (int o = 32; o > 0; o >>= 1) { s += __shfl_down(s, o); ss += __shfl_down(ss, o); }
  __shared__ float red[8];
  if ((tid & 63) == 0) { red[(tid >> 6) * 2] = s; red[(tid >> 6) * 2 + 1] = ss; }
  __syncthreads();
  float ts = 0.f, tss = 0.f;
#pragma unroll
  for (int i = 0; i < 4; i++) { ts += red[i * 2]; tss += red[i * 2 + 1]; }
  const float mu = ts * (1.f / 1024.f);
  const float var = tss * (1.f / 1024.f) - mu * mu;
  const float rs = rsqrtf(var + 1e-3f);
  __hip_bfloat16* dst = out + (size_t)row * HID_;
#pragma unroll
  for (int i = 0; i < 4; i++) {
    int c = i * 256 + tid;
    dst[c] = __float2bfloat16((x[i] - mu) * rs * ldin(gamma, c, md) + ldin(beta, c, md));
  }
}

__global__ __launch_bounds__(256) void ln_q_kernel(
    const void* __restrict__ qry,
    const void* __restrict__ gamma, const void* __restrict__ beta,
    __hip_bfloat16* __restrict__ out, const int* __restrict__ mode) {
  const int md = *mode;
  const int row = blockIdx.x;  // 0..B*Q-1
  const size_t base = (size_t)row * HID_;
  const int tid = threadIdx.x;
  float x[4];
  float s = 0.f, ss = 0.f;
#pragma unroll
  for (int i = 0; i < 4; i++) {
    x[i] = ldin(qry, base + i * 256 + tid, md);
    s += x[i]; ss += x[i] * x[i];
  }
#pragma unroll
  for (int o = 32; o > 0; o >>= 1) { s += __shfl_down(s, o); ss += __shfl_down(ss, o); }
  __shared__ float red[8];
  if ((tid & 63) == 0) { red[(tid >> 6) * 2] = s; red[(tid >> 6) * 2 + 1] = ss; }
  __syncthreads();
  float ts = 0.f, tss = 0.f;
#pragma unroll
  for (int i = 0; i < 4; i++) { ts += red[i * 2]; tss += red[i * 2 + 1]; }
  const float mu = ts * (1.f / 1024.f);
  const float var = tss * (1.f / 1024.f) - mu * mu;
  const float rs = rsqrtf(var + 1e-3f);
  __hip_bfloat16* dst = out + (size_t)row * HID_;
#pragma unroll
  for (int i = 0; i < 4; i++) {
    int c = i * 256 + tid;
    dst[c] = __float2bfloat16((x[i] - mu) * rs * ldin(gamma, c, md) + ldin(beta, c, md));
  }
}

// ---------------- sinusoidal position embedding, positions K-1..0 ----------------
__global__ __launch_bounds__(256) void posemb_kernel(__hip_bfloat16* __restrict__ pe) {
  const int p = blockIdx.x;
  const float pos = (float)(KL_ - 1 - p);
  const int tid = threadIdx.x;
#pragma unroll
  for (int i = 0; i < 4; i++) {
    int c = tid * 4 + i;
    int f = (c < 512) ? c : c - 512;
    float invf = fexp2(-(float)f * (13.287712379549449f / 512.0f));
    float a = pos * invf;
    float v = (c < 512) ? __sinf(a) : __cosf(a);
    pe[(size_t)p * HID_ + c] = __float2bfloat16(v);
  }
}

// ---------------- GEMM core: C = A @ BT^T (both bf16, K=1024), 128x128 tile ----------------
template <int WRITE_MODE_SWITCH>
__device__ __forceinline__ void gemm_body(const __hip_bfloat16* __restrict__ A,
                                          const __hip_bfloat16* __restrict__ BT,
                                          void* __restrict__ C, int md, float scl) {
  __shared__ __attribute__((aligned(16))) __hip_bfloat16 sA[128 * 32];
  __shared__ __attribute__((aligned(16))) __hip_bfloat16 sB[128 * 32];
  const int tid = threadIdx.x;
  const int lane = tid & 63;
  const int w = tid >> 6;
  const int quad = lane >> 4, l16 = lane & 15;
  const int m0 = blockIdx.x * 128;
  const int n0 = blockIdx.y * 128;
  const int wm = (w >> 1) * 64, wn = (w & 1) * 64;
  const f32x4 fz = {0.f, 0.f, 0.f, 0.f};

  f32x4 acc[4][4];
#pragma unroll
  for (int i = 0; i < 4; i++)
#pragma unroll
    for (int j = 0; j < 4; j++) acc[i][j] = fz;

  for (int kk = 0; kk < HID_ / 32; kk++) {
    const int k0 = kk * 32;
    __syncthreads();
#pragma unroll
    for (int t = 0; t < 2; t++) {
      int c = (w * 2 + t) * 64 + lane;
      int row = c >> 2;
      int cid = (c & 3) ^ (row & 3);
      async_copy16(A + (size_t)(m0 + row) * HID_ + k0 + cid * 8, (char*)sA + c * 16);
      async_copy16(BT + (size_t)(n0 + row) * HID_ + k0 + cid * 8, (char*)sB + c * 16);
    }
    __syncthreads();
    short8 af[4], bf[4];
#pragma unroll
    for (int mt = 0; mt < 4; mt++) {
      int r = wm + mt * 16 + l16;
      af[mt] = *(const short8*)((const char*)sA + r * 64 + ((quad ^ (r & 3)) * 16));
    }
#pragma unroll
    for (int nt = 0; nt < 4; nt++) {
      int r = wn + nt * 16 + l16;
      bf[nt] = *(const short8*)((const char*)sB + r * 64 + ((quad ^ (r & 3)) * 16));
    }
#pragma unroll
    for (int mt = 0; mt < 4; mt++)
#pragma unroll
      for (int nt = 0; nt < 4; nt++)
        acc[mt][nt] = __builtin_amdgcn_mfma_f32_16x16x32_bf16(af[mt], bf[nt], acc[mt][nt], 0, 0, 0);
  }
#pragma unroll
  for (int mt = 0; mt < 4; mt++)
#pragma unroll
    for (int nt = 0; nt < 4; nt++)
#pragma unroll
      for (int rg = 0; rg < 4; rg++) {
        int r = m0 + wm + mt * 16 + quad * 4 + rg;
        int cc = n0 + wn + nt * 16 + l16;
        size_t idx = (size_t)r * HID_ + cc;
        if (WRITE_MODE_SWITCH && md) ((float*)C)[idx] = acc[mt][nt][rg];
        else ((__hip_bfloat16*)C)[idx] = __float2bfloat16(acc[mt][nt][rg] * scl);
      }
}

__global__ __launch_bounds__(256) void gemm_bt128(const __hip_bfloat16* __restrict__ A,
                                                  const __hip_bfloat16* __restrict__ BT,
                                                  __hip_bfloat16* __restrict__ C, float scl) {
  gemm_body<0>(A, BT, (void*)C, 0, scl);
}

__global__ __launch_bounds__(256) void gemm_out(const __hip_bfloat16* __restrict__ A,
                                                const __hip_bfloat16* __restrict__ BT,
                                                void* __restrict__ C,
                                                const int* __restrict__ mode) {
  gemm_body<1>(A, BT, C, *mode, 1.0f);
}

// ---------------- bias dots (pre-scaled by log2e/64) ----------------
__global__ __launch_bounds__(256) void cbias_kernel(const __hip_bfloat16* __restrict__ kp,
                                                    const void* __restrict__ rwb,
                                                    float* __restrict__ cb,
                                                    const int* __restrict__ mode) {
  const int md = *mode;
  const int idx = blockIdx.x * 256 + threadIdx.x;  // B*H*KL
  const int j = idx % KL_;
  const int h = (idx / KL_) % H_;
  const int b = idx / (KL_ * H_);
  const __hip_bfloat16* kr = kp + ((size_t)b * KL_ + j) * HID_ + h * D_;
  float s = 0.f;
#pragma unroll
  for (int t = 0; t < 8; t++) {
    short8 v = *(const short8*)(kr + t * 8);
#pragma unroll
    for (int u = 0; u < 8; u++) {
      short sb = v[u];
      s += __bfloat162float(*(__hip_bfloat16*)&sb) * ldin(rwb, h * D_ + t * 8 + u, md);
    }
  }
  cb[idx] = s * LSCL;
}

__global__ __launch_bounds__(256) void ebias_kernel(const __hip_bfloat16* __restrict__ relp,
                                                    const void* __restrict__ rrb,
                                                    float* __restrict__ eb,
                                                    const int* __restrict__ mode) {
  const int md = *mode;
  const int idx = blockIdx.x * 256 + threadIdx.x;  // H*(KL+EPAD)
  const int p = idx % (KL_ + EPAD);
  const int h = idx / (KL_ + EPAD);
  const int pc = p < KL_ ? p : KL_ - 1;            // pad rows: finite junk (masked downstream)
  const __hip_bfloat16* rr = relp + (size_t)pc * HID_ + h * D_;
  float s = 0.f;
#pragma unroll
  for (int t = 0; t < 8; t++) {
    short8 v = *(const short8*)(rr + t * 8);
#pragma unroll
    for (int u = 0; u < 8; u++) {
      short sb = v[u];
      s += __bfloat162float(*(__hip_bfloat16*)&sb) * ldin(rrb, h * D_ + t * 8 + u, md);
    }
  }
  eb[idx] = s * LSCL;
}

// ---------------- fused relative attention ----------------
// grid 1024 flat (XCD-remapped), block 256 (4 waves). Logits in log2 units. LDS = 51 KB
// (K tile + V^T tile + sTP) -> 3 blocks/CU. rel A-frags streamed from global through a
// depth-4 rotating register buffer (32 VGPRs, no spill). 2 barriers/tile.
__global__ __launch_bounds__(256, 3) void attn_kernel(
    const __hip_bfloat16* __restrict__ qp, const __hip_bfloat16* __restrict__ kp,
    const __hip_bfloat16* __restrict__ vpt, const __hip_bfloat16* __restrict__ relp,
    const float* __restrict__ cb, const float* __restrict__ eb,
    const void* __restrict__ spanv, __hip_bfloat16* __restrict__ attn_out,
    const int* __restrict__ mode) {
  const int md = *mode;
  const int bid = blockIdx.x;
  const int bh = (bid & 7) + 8 * (bid >> 8);
  const int i0 = ((bid >> 3) & 31) * RT_;
  const int b = bh >> 4, h = bh & 15;

  const int tid = threadIdx.x;
  const int lane = tid & 63;
  const int w = tid >> 6;
  const int quad = lane >> 4, l16 = lane & 15;
  const int di = w * 16 + l16;        // this thread's softmax row (block-local)
  const int iRow = i0 + di;
  const f32x4 fz = {0.f, 0.f, 0.f, 0.f};

  __shared__ __attribute__((aligned(16))) __hip_bfloat16 sk[128 * 64];    // 16 KB K tile (q staged here first)
  __shared__ __attribute__((aligned(16))) __hip_bfloat16 svt[64 * 128];   // 16 KB V^T tile
  __shared__ __attribute__((aligned(16))) short sTP[64 * 152];            // 19 KB T-band/P rows

  const int rb = di * 304;            // private row base (bytes), 16B-aligned

  const __hip_bfloat16* kbase = kp + (size_t)b * KL_ * HID_ + h * D_;
  const __hip_bfloat16* vtb = vpt + ((size_t)(b * H_ + h)) * D_ * KL_;
  const __hip_bfloat16* relh = relp + h * D_;
  const float* cbb = cb + (size_t)(b * H_ + h) * KL_;
  const float* ebb = eb + (size_t)h * (KL_ + EPAD);
  const float sv = ldin(spanv, h, md);
  const float svQ = sv * (float)Q_;
  const int pb0 = Q_ - RT_ - i0;
  const int wof = (3 - w) * 16;       // this wave's T-band p-window offset
  const int ntiles = ((M_ + i0 + RT_ - 1) >> 7) + 1;

  // ---- stage q once via sk, read own-row B-fragments ----
  {
    const __hip_bfloat16* qb = qp + ((size_t)(b * Q_ + i0)) * HID_ + h * D_;
#pragma unroll
    for (int t = 0; t < 2; t++) {
      int c = (w * 2 + t) * 64 + lane;
      int row = c >> 3;
      int cid = (c & 7) ^ (row & 7);
      async_copy16(qb + (size_t)row * HID_ + cid * 8, (char*)sk + c * 16);
    }
  }
  __syncthreads();
  short8 qf[2];
#pragma unroll
  for (int ks = 0; ks < 2; ks++)
    qf[ks] = *(const short8*)((const char*)sk + di * 128 + (((ks * 4 + quad) ^ (di & 7)) * 16));

  float mrow = -3e38f, lrow = 0.f, dfrow = 0.f;
  f32x4 oacc[4];
#pragma unroll
  for (int dt = 0; dt < 4; dt++) oacc[dt] = fz;

  for (int kt = 0; kt < ntiles; kt++) {
    const int j0 = kt * WT_;
    const int pbase = pb0 + j0;

    __syncthreads();  // A: prior tile's sk/svt/q-frag consumers done
    // ---- DMA staging: K (4), V^T (4) ----
#pragma unroll
    for (int t = 0; t < 4; t++) {
      int c = (w * 4 + t) * 64 + lane;
      int row = c >> 3;
      int cid = (c & 7) ^ (row & 7);
      async_copy16(kbase + (size_t)(j0 + row) * HID_ + cid * 8, (char*)sk + c * 16);
    }
#pragma unroll
    for (int t = 0; t < 4; t++) {
      int c = (w * 4 + t) * 64 + lane;
      int row = c >> 4;
      int cid = (c & 15) ^ (row & 15);
      async_copy16(vtb + (size_t)row * KL_ + j0 + cid * 8, (char*)svt + c * 16);
    }
    __syncthreads();  // B: DMA drained (32 KB)

    // ---- rel stream: depth-4 rotating buffer (32 VGPRs, no spill) ----
    short8 rrf[4][2];
#pragma unroll
    for (int mt = 0; mt < 4; mt++) {
      int p = pbase + wof + mt * 16 + l16;
      p = p < KL_ ? p : KL_ - 1;   // clamped rows feed only masked cols
      const __hip_bfloat16* rr = relh + (size_t)p * HID_;
#pragma unroll
      for (int ks = 0; ks < 2; ks++)
        rrf[mt][ks] = *(const short8*)(rr + ks * 32 + quad * 8);
    }

    // ---- S^T[j][i] = K . Q^T (first 4 rel loads in flight behind this) ----
    f32x4 S[8];
#pragma unroll
    for (int mt = 0; mt < 8; mt++) S[mt] = fz;
#pragma unroll
    for (int mt = 0; mt < 8; mt++) {
      int r = mt * 16 + l16;
#pragma unroll
      for (int ks = 0; ks < 2; ks++) {
        short8 af = *(const short8*)((const char*)sk + r * 128 + (((ks * 4 + quad) ^ (r & 7)) * 16));
        S[mt] = __builtin_amdgcn_mfma_f32_16x16x32_bf16(af, qf[ks], S[mt], 0, 0, 0);
      }
    }

    // ---- T band (wave's 144-col window): consume slot, refill with mt+4 ----
#pragma unroll
    for (int mt = 0; mt < 9; mt++) {
      f32x4 T = fz;
#pragma unroll
      for (int ks = 0; ks < 2; ks++)
        T = __builtin_amdgcn_mfma_f32_16x16x32_bf16(rrf[mt & 3][ks], qf[ks], T, 0, 0, 0);
      if (mt + 4 < 9) {
        int p = pbase + wof + (mt + 4) * 16 + l16;
        p = p < KL_ ? p : KL_ - 1;
        const __hip_bfloat16* rr = relh + (size_t)p * HID_;
#pragma unroll
        for (int ks = 0; ks < 2; ks++)
          rrf[mt & 3][ks] = *(const short8*)(rr + ks * 32 + quad * 8);
      }
      const int lo = mt * 16 + quad * 4;              // local band offset [0,144)
      f32x4 e4 = *(const f32x4*)(ebb + pbase + wof + lo);
      short4v pk;
#pragma unroll
      for (int rg = 0; rg < 4; rg++) pk[rg] = bfbits(T[rg] + e4[rg]);
      *(short4v*)((char*)sTP + rb + lo * 2) = pk;
    }

    // ---- gather with per-row shift (own row, in-order DS) ----
#pragma unroll
    for (int mt = 0; mt < 8; mt++)
#pragma unroll
      for (int rg = 0; rg < 4; rg++) {
        int tcl = 15 - l16 + mt * 16 + quad * 4 + rg;
        S[mt][rg] += __bfloat162float(*(const __hip_bfloat16*)((const char*)sTP + rb + tcl * 2));
      }

    // ---- logits (log2 units), causal mask only on tiles that can need it ----
    const bool causalT = (j0 + WT_ - 1 - i0) > M_;
    float mnew = mrow;
#pragma unroll
    for (int mt = 0; mt < 8; mt++) {
      f32x4 cb4 = *(const f32x4*)(cbb + j0 + mt * 16 + quad * 4);
#pragma unroll
      for (int rg = 0; rg < 4; rg++) {
        float v = S[mt][rg] + cb4[rg];
        if (causalT) {
          int j = j0 + mt * 16 + quad * 4 + rg;
          if (j - iRow > M_) v = -1e30f;
        }
        S[mt][rg] = v;
        mnew = fmaxf(mnew, v);
      }
    }
    mnew = fmaxf(mnew, __shfl_xor(mnew, 16));
    mnew = fmaxf(mnew, __shfl_xor(mnew, 32));
    const float alpha = fexp2(mrow - mnew);
    mrow = mnew;
    lrow *= alpha; dfrow *= alpha;
    float aR[4];
#pragma unroll
    for (int rg = 0; rg < 4; rg++) aR[rg] = __shfl(alpha, quad * 4 + rg);
#pragma unroll
    for (int dt = 0; dt < 4; dt++)
#pragma unroll
      for (int rg = 0; rg < 4; rg++) oacc[dt][rg] *= aR[rg];

    // ---- P = exp2(S-m); span deficit only on tiles overlapping the ramp ----
    const bool maskT = (j0 + WT_ > M_) && ((float)j0 < (float)M_ + 33.f - svQ);
#pragma unroll
    for (int mt = 0; mt < 8; mt++) {
      short4v pk;
#pragma unroll
      for (int rg = 0; rg < 4; rg++) {
        float pv = fexp2(S[mt][rg] - mrow);
        lrow += pv;
        float pm = pv;
        if (maskT) {
          int j = j0 + mt * 16 + quad * 4 + rg;
          if (j >= M_) {
            float t0 = (float)(j - M_) + svQ;
            float mk = fminf(fmaxf(t0 * (1.0f / 33.0f), 0.f), 1.f);
            pm = pv * mk;
            dfrow += pv - pm;
          }
        }
        pk[rg] = bfbits(pm);
      }
      *(short4v*)((char*)sTP + rb + (mt * 16 + quad * 4) * 2) = pk;
    }

    // ---- PV: A = P (own rows, b128 from sTP), B = V^T rows from svt ----
#pragma unroll
    for (int ks = 0; ks < 4; ks++) {
      short8 af = *(const short8*)((const char*)sTP + rb + ks * 64 + quad * 16);
#pragma unroll
      for (int dt = 0; dt < 4; dt++) {
        int r = dt * 16 + l16;
        short8 bfv = *(const short8*)((const char*)svt + r * 256 + (((ks * 4 + quad) ^ (r & 15)) * 16));
        oacc[dt] = __builtin_amdgcn_mfma_f32_16x16x32_bf16(af, bfv, oacc[dt], 0, 0, 0);
      }
    }
  }

  // ---- epilogue: lm = lr - deficit ----
  lrow += __shfl_xor(lrow, 16);  lrow += __shfl_xor(lrow, 32);
  dfrow += __shfl_xor(dfrow, 16); dfrow += __shfl_xor(dfrow, 32);
  float lr4[4], df4[4];
#pragma unroll
  for (int rg = 0; rg < 4; rg++) {
    lr4[rg] = __shfl(lrow, quad * 4 + rg);
    df4[rg] = __shfl(dfrow, quad * 4 + rg);
  }
#pragma unroll
  for (int dt = 0; dt < 4; dt++)
#pragma unroll
    for (int rg = 0; rg < 4; rg++) {
      int i = i0 + w * 16 + quad * 4 + rg;
      float denom = (lr4[rg] - df4[rg]) + 1e-8f * lr4[rg];
      float ov = oacc[dt][rg] / denom;
      attn_out[((size_t)(b * Q_ + i)) * HID_ + h * D_ + dt * 16 + l16] = __float2bfloat16(ov);
    }
}

// ---------------- launcher ----------------
extern "C" void kernel_launch(void* const* d_in, const int* in_sizes, int n_in,
                              void* d_out, int out_size, void* d_ws, size_t ws_size,
                              hipStream_t stream) {
  const void* query  = d_in[0];
  const void* memory = d_in[1];
  const void* Wq = d_in[2];
  const void* Wk = d_in[3];
  const void* Wv = d_in[4];
  const void* Wo = d_in[5];
  const void* Wr = d_in[6];
  const void* gmem = d_in[7];
  const void* bmem = d_in[8];
  const void* gq = d_in[9];
  const void* bq = d_in[10];
  const void* rwb = d_in[11];
  const void* rrb = d_in[12];
  const void* spanv = d_in[13];

  char* ws = (char*)d_ws;
  size_t off = 0;
  auto alloc = [&](size_t bytes) -> char* {
    char* p = ws + off;
    off += (bytes + 255) & ~(size_t)255;
    return p;
  };
  int* flag = (int*)alloc(256);
  const size_t SZ_W = (size_t)HID_ * HID_ * 2;
  __hip_bfloat16* wqT = (__hip_bfloat16*)alloc(SZ_W);
  __hip_bfloat16* wkT = (__hip_bfloat16*)alloc(SZ_W);
  __hip_bfloat16* wvT = (__hip_bfloat16*)alloc(SZ_W);
  __hip_bfloat16* wrT = (__hip_bfloat16*)alloc(SZ_W);
  __hip_bfloat16* woT = (__hip_bfloat16*)alloc(SZ_W);
  __hip_bfloat16* kvln = (__hip_bfloat16*)alloc((size_t)B_ * KL_ * HID_ * 2);
  __hip_bfloat16* qln  = (__hip_bfloat16*)alloc((size_t)B_ * Q_ * HID_ * 2);
  __hip_bfloat16* pe   = (__hip_bfloat16*)alloc((size_t)KL_ * HID_ * 2);
  __hip_bfloat16* qpb  = (__hip_bfloat16*)alloc((size_t)B_ * Q_ * HID_ * 2);
  __hip_bfloat16* kpb  = (__hip_bfloat16*)alloc((size_t)B_ * KL_ * HID_ * 2);
  __hip_bfloat16* vpb  = (__hip_bfloat16*)alloc((size_t)B_ * KL_ * HID_ * 2);
  __hip_bfloat16* relp = (__hip_bfloat16*)alloc((size_t)KL_ * HID_ * 2);
  __hip_bfloat16* aout = (__hip_bfloat16*)alloc((size_t)B_ * Q_ * HID_ * 2);
  float* cbf = (float*)alloc((size_t)B_ * H_ * KL_ * 4);
  float* ebf = (float*)alloc((size_t)H_ * (KL_ + EPAD) * 4);
  __hip_bfloat16* vptb = kvln;  // alias: kvln dead after the k/v projection GEMMs

  dim3 tb(256);
  detect_kernel<<<dim3(1), tb, 0, stream>>>((const unsigned int*)query, flag);

  wt5_kernel<<<dim3(16, 16, 5), tb, 0, stream>>>(Wq, Wk, Wv, Wr, Wo,
                                                 wqT, wkT, wvT, wrT, woT, flag);

  ln_kv_kernel<<<dim3(B_ * KL_), tb, 0, stream>>>(memory, query, gmem, bmem, kvln, flag);
  ln_q_kernel<<<dim3(B_ * Q_), tb, 0, stream>>>(query, gq, bq, qln, flag);
  posemb_kernel<<<dim3(KL_), tb, 0, stream>>>(pe);

  gemm_bt128<<<dim3(B_ * Q_ / 128, HID_ / 128), tb, 0, stream>>>(qln, wqT, qpb, LSCL);
  gemm_bt128<<<dim3(B_ * KL_ / 128, HID_ / 128), tb, 0, stream>>>(kvln, wkT, kpb, 1.0f);
  gemm_bt128<<<dim3(B_ * KL_ / 128, HID_ / 128), tb, 0, stream>>>(kvln, wvT, vpb, 1.0f);
  gemm_bt128<<<dim3(KL_ / 128, HID_ / 128), tb, 0, stream>>>(pe, wrT, relp, 1.0f);

  vpt_kernel<<<dim3(KL_ / 64, B_ * H_), tb, 0, stream>>>(vpb, vptb);
  cbias_kernel<<<dim3(B_ * H_ * KL_ / 256), tb, 0, stream>>>(kpb, rwb, cbf, flag);
  ebias_kernel<<<dim3(H_ * (KL_ + EPAD) / 256), tb, 0, stream>>>(relp, rrb, ebf, flag);

  attn_kernel<<<dim3((Q_ / RT_) * H_ * B_), tb, 0, stream>>>(qpb, kpb, vptb, relp, cbf, ebf, spanv, aout, flag);

  gemm_out<<<dim3(B_ * Q_ / 128, HID_ / 128), tb, 0, stream>>>(aout, woT, d_out, flag);

  (void)in_sizes; (void)n_in; (void)out_size; (void)ws_size;
}

// Round 10
// 605.949 us; speedup vs baseline: 1.3259x; 1.2396x over previous
//
#include <hip/hip_runtime.h>
#include <hip/hip_bf16.h>
#include <math.h>

#define B_   2
#define Q_   2048
#define M_   2048
#define H_   16
#define D_   64
#define HID_ 1024
#define KL_  4096
#define RT_  64      // q rows per attention block
#define WT_  128     // k cols per attention tile
#define EPAD 256     // e-table tail padding (band reads past KL land here)
#define LSCL 0.022542110013890053f   // log2(e)/64 — logits kept in log2 units
#define NCB  (B_ * H_ * KL_)         // cbias element count
#define NEB  (H_ * (KL_ + EPAD))     // ebias element count

typedef short short8 __attribute__((ext_vector_type(8)));
typedef short short4v __attribute__((ext_vector_type(4)));
typedef float f32x4 __attribute__((ext_vector_type(4)));

__device__ __forceinline__ void async_copy16(const void* g, void* l) {
  __builtin_amdgcn_global_load_lds((const __attribute__((address_space(1))) unsigned int*)g,
                                   (__attribute__((address_space(3))) unsigned int*)l,
                                   16, 0, 0);
}

// read input element i as float, md=1 -> fp32 buffer, md=0 -> bf16 buffer
__device__ __forceinline__ float ldin(const void* p, size_t i, int md) {
  return md ? ((const float*)p)[i] : __bfloat162float(((const __hip_bfloat16*)p)[i]);
}

__device__ __forceinline__ short bfbits(float v) {
  __hip_bfloat16 t = __float2bfloat16(v);
  return *(short*)&t;
}

// fast 2^x: lowers to v_exp_f32 (HW computes 2^x natively)
__device__ __forceinline__ float fexp2(float x) { return exp2f(x); }

// ---------------- dtype detector: writes 1 if inputs are fp32, else 0 ----------------
__global__ __launch_bounds__(256) void detect_kernel(const unsigned int* __restrict__ q,
                                                     int* __restrict__ flag) {
  __shared__ int cnt;
  if (threadIdx.x == 0) cnt = 0;
  __syncthreads();
  int ins = 0;
#pragma unroll
  for (int i = 0; i < 4; i++) {
    unsigned int u = q[threadIdx.x * 4 + i];
    int e0 = (int)((u >> 7) & 0xffu);
    int e1 = (int)((u >> 23) & 0xffu);
    if (e0 == 0xff || e0 < 102 || e0 > 140) ins++;
    if (e1 == 0xff || e1 < 102 || e1 > 140) ins++;
  }
  atomicAdd(&cnt, ins);
  __syncthreads();
  if (threadIdx.x == 0) *flag = (cnt > 512) ? 1 : 0;
}

// ---------------- fused weight transposes: wt[n][k] = src[k][n], 5 x 1024x1024 ----------------
__global__ __launch_bounds__(256) void wt5_kernel(
    const void* __restrict__ s0, const void* __restrict__ s1, const void* __restrict__ s2,
    const void* __restrict__ s3, const void* __restrict__ s4,
    __hip_bfloat16* __restrict__ d0, __hip_bfloat16* __restrict__ d1,
    __hip_bfloat16* __restrict__ d2, __hip_bfloat16* __restrict__ d3,
    __hip_bfloat16* __restrict__ d4, const int* __restrict__ mode) {
  const int md = *mode;
  const void* src; __hip_bfloat16* dst;
  switch (blockIdx.z) {
    case 0: src = s0; dst = d0; break;
    case 1: src = s1; dst = d1; break;
    case 2: src = s2; dst = d2; break;
    case 3: src = s3; dst = d3; break;
    default: src = s4; dst = d4; break;
  }
  const int r0 = blockIdx.x * 64, c0 = blockIdx.y * 64;
  __shared__ __hip_bfloat16 t[64][65];
  const int tid = threadIdx.x;
  const int col = tid & 63, r4 = tid >> 6;
#pragma unroll
  for (int i = 0; i < 16; i++)
    t[r4 + i * 4][col] = __float2bfloat16(ldin(src, (size_t)(r0 + r4 + i * 4) * HID_ + c0 + col, md));
  __syncthreads();
#pragma unroll
  for (int i = 0; i < 16; i++)
    dst[(size_t)(c0 + r4 + i * 4) * HID_ + r0 + col] = t[col][r4 + i * 4];
}

// ---------------- V transpose: vpt[b][h][d][j] = vp[b*K+j][h*64+d] ----------------
__global__ __launch_bounds__(256) void vpt_kernel(const __hip_bfloat16* __restrict__ vp,
                                                  __hip_bfloat16* __restrict__ vpt) {
  const int jt = blockIdx.x * 64;
  const int bh = blockIdx.y;
  const int b = bh / H_, h = bh % H_;
  __shared__ __hip_bfloat16 t[64][65];
  const int tid = threadIdx.x;
  const int col = tid & 63, r4 = tid >> 6;
#pragma unroll
  for (int i = 0; i < 16; i++) {
    int j = r4 + i * 4;
    t[j][col] = vp[((size_t)b * KL_ + jt + j) * HID_ + h * D_ + col];
  }
  __syncthreads();
#pragma unroll
  for (int i = 0; i < 16; i++) {
    int d = r4 + i * 4;
    vpt[(((size_t)b * H_ + h) * D_ + d) * KL_ + jt + col] = t[col][d];
  }
}

// ---------------- LayerNorm over concat(memory, query) rows ----------------
__global__ __launch_bounds__(256) void ln_kv_kernel(
    const void* __restrict__ mem, const void* __restrict__ qry,
    const void* __restrict__ gamma, const void* __restrict__ beta,
    __hip_bfloat16* __restrict__ out, const int* __restrict__ mode) {
  const int md = *mode;
  const int row = blockIdx.x;  // 0..B*KL-1
  const int b = row / KL_, j = row % KL_;
  const void* src;
  size_t base;
  if (j < M_) { src = mem; base = ((size_t)b * M_ + j) * HID_; }
  else        { src = qry; base = ((size_t)b * Q_ + (j - M_)) * HID_; }
  const int tid = threadIdx.x;
  float x[4];
  float s = 0.f, ss = 0.f;
#pragma unroll
  for (int i = 0; i < 4; i++) {
    x[i] = ldin(src, base + i * 256 + tid, md);
    s += x[i]; ss += x[i] * x[i];
  }
#pragma unroll
  for (int o = 32; o > 0; o >>= 1) { s += __shfl_down(s, o); ss += __shfl_down(ss, o); }
  __shared__ float red[8];
  if ((tid & 63) == 0) { red[(tid >> 6) * 2] = s; red[(tid >> 6) * 2 + 1] = ss; }
  __syncthreads();
  float ts = 0.f, tss = 0.f;
#pragma unroll
  for (int i = 0; i < 4; i++) { ts += red[i * 2]; tss += red[i * 2 + 1]; }
  const float mu = ts * (1.f / 1024.f);
  const float var = tss * (1.f / 1024.f) - mu * mu;
  const float rs = rsqrtf(var + 1e-3f);
  __hip_bfloat16* dst = out + (size_t)row * HID_;
#pragma unroll
  for (int i = 0; i < 4; i++) {
    int c = i * 256 + tid;
    dst[c] = __float2bfloat16((x[i] - mu) * rs * ldin(gamma, c, md) + ldin(beta, c, md));
  }
}

__global__ __launch_bounds__(256) void ln_q_kernel(
    const void* __restrict__ qry,
    const void* __restrict__ gamma, const void* __restrict__ beta,
    __hip_bfloat16* __restrict__ out, const int* __restrict__ mode) {
  const int md = *mode;
  const int row = blockIdx.x;  // 0..B*Q-1
  const size_t base = (size_t)row * HID_;
  const int tid = threadIdx.x;
  float x[4];
  float s = 0.f, ss = 0.f;
#pragma unroll
  for (int i = 0; i < 4; i++) {
    x[i] = ldin(qry, base + i * 256 + tid, md);
    s += x[i]; ss += x[i] * x[i];
  }
#pragma unroll
  for (int o = 32; o > 0; o >>= 1) { s += __shfl_down(s, o); ss += __shfl_down(ss, o); }
  __shared__ float red[8];
  if ((tid & 63) == 0) { red[(tid >> 6) * 2] = s; red[(tid >> 6) * 2 + 1] = ss; }
  __syncthreads();
  float ts = 0.f, tss = 0.f;
#pragma unroll
  for (int i = 0; i < 4; i++) { ts += red[i * 2]; tss += red[i * 2 + 1]; }
  const float mu = ts * (1.f / 1024.f);
  const float var = tss * (1.f / 1024.f) - mu * mu;
  const float rs = rsqrtf(var + 1e-3f);
  __hip_bfloat16* dst = out + (size_t)row * HID_;
#pragma unroll
  for (int i = 0; i < 4; i++) {
    int c = i * 256 + tid;
    dst[c] = __float2bfloat16((x[i] - mu) * rs * ldin(gamma, c, md) + ldin(beta, c, md));
  }
}

// ---------------- sinusoidal position embedding, positions K-1..0 ----------------
__global__ __launch_bounds__(256) void posemb_kernel(__hip_bfloat16* __restrict__ pe) {
  const int p = blockIdx.x;
  const float pos = (float)(KL_ - 1 - p);
  const int tid = threadIdx.x;
#pragma unroll
  for (int i = 0; i < 4; i++) {
    int c = tid * 4 + i;
    int f = (c < 512) ? c : c - 512;
    float invf = fexp2(-(float)f * (13.287712379549449f / 512.0f));
    float a = pos * invf;
    float v = (c < 512) ? __sinf(a) : __cosf(a);
    pe[(size_t)p * HID_ + c] = __float2bfloat16(v);
  }
}

// ---------------- GEMM core: C = A @ BT^T (both bf16, K=1024), 128x128 tile ----------------
template <int WRITE_MODE_SWITCH>
__device__ __forceinline__ void gemm_body(const __hip_bfloat16* __restrict__ A,
                                          const __hip_bfloat16* __restrict__ BT,
                                          void* __restrict__ C, int md, float scl) {
  __shared__ __attribute__((aligned(16))) __hip_bfloat16 sA[128 * 32];
  __shared__ __attribute__((aligned(16))) __hip_bfloat16 sB[128 * 32];
  const int tid = threadIdx.x;
  const int lane = tid & 63;
  const int w = tid >> 6;
  const int quad = lane >> 4, l16 = lane & 15;
  const int m0 = blockIdx.x * 128;
  const int n0 = blockIdx.y * 128;
  const int wm = (w >> 1) * 64, wn = (w & 1) * 64;
  const f32x4 fz = {0.f, 0.f, 0.f, 0.f};

  f32x4 acc[4][4];
#pragma unroll
  for (int i = 0; i < 4; i++)
#pragma unroll
    for (int j = 0; j < 4; j++) acc[i][j] = fz;

  for (int kk = 0; kk < HID_ / 32; kk++) {
    const int k0 = kk * 32;
    __syncthreads();
#pragma unroll
    for (int t = 0; t < 2; t++) {
      int c = (w * 2 + t) * 64 + lane;
      int row = c >> 2;
      int cid = (c & 3) ^ (row & 3);
      async_copy16(A + (size_t)(m0 + row) * HID_ + k0 + cid * 8, (char*)sA + c * 16);
      async_copy16(BT + (size_t)(n0 + row) * HID_ + k0 + cid * 8, (char*)sB + c * 16);
    }
    __syncthreads();
    short8 af[4], bf[4];
#pragma unroll
    for (int mt = 0; mt < 4; mt++) {
      int r = wm + mt * 16 + l16;
      af[mt] = *(const short8*)((const char*)sA + r * 64 + ((quad ^ (r & 3)) * 16));
    }
#pragma unroll
    for (int nt = 0; nt < 4; nt++) {
      int r = wn + nt * 16 + l16;
      bf[nt] = *(const short8*)((const char*)sB + r * 64 + ((quad ^ (r & 3)) * 16));
    }
#pragma unroll
    for (int mt = 0; mt < 4; mt++)
#pragma unroll
      for (int nt = 0; nt < 4; nt++)
        acc[mt][nt] = __builtin_amdgcn_mfma_f32_16x16x32_bf16(af[mt], bf[nt], acc[mt][nt], 0, 0, 0);
  }
#pragma unroll
  for (int mt = 0; mt < 4; mt++)
#pragma unroll
    for (int nt = 0; nt < 4; nt++)
#pragma unroll
      for (int rg = 0; rg < 4; rg++) {
        int r = m0 + wm + mt * 16 + quad * 4 + rg;
        int cc = n0 + wn + nt * 16 + l16;
        size_t idx = (size_t)r * HID_ + cc;
        if (WRITE_MODE_SWITCH && md) ((float*)C)[idx] = acc[mt][nt][rg];
        else ((__hip_bfloat16*)C)[idx] = __float2bfloat16(acc[mt][nt][rg] * scl);
      }
}

__global__ __launch_bounds__(256) void gemm_bt128(const __hip_bfloat16* __restrict__ A,
                                                  const __hip_bfloat16* __restrict__ BT,
                                                  __hip_bfloat16* __restrict__ C, float scl) {
  gemm_body<0>(A, BT, (void*)C, 0, scl);
}

__global__ __launch_bounds__(256) void gemm_out(const __hip_bfloat16* __restrict__ A,
                                                const __hip_bfloat16* __restrict__ BT,
                                                void* __restrict__ C,
                                                const int* __restrict__ mode) {
  gemm_body<1>(A, BT, C, *mode, 1.0f);
}

// ---- dual GEMM: BT is the contiguous [wkT; wvT] block (2048 rows); block-uniform output select ----
__global__ __launch_bounds__(256) void gemm_dual(const __hip_bfloat16* __restrict__ A,
                                                 const __hip_bfloat16* __restrict__ BT,
                                                 __hip_bfloat16* __restrict__ C0,
                                                 __hip_bfloat16* __restrict__ C1) {
  __shared__ __attribute__((aligned(16))) __hip_bfloat16 sA[128 * 32];
  __shared__ __attribute__((aligned(16))) __hip_bfloat16 sB[128 * 32];
  const int tid = threadIdx.x;
  const int lane = tid & 63;
  const int w = tid >> 6;
  const int quad = lane >> 4, l16 = lane & 15;
  const int m0 = blockIdx.x * 128;
  const int n0 = blockIdx.y * 128;  // 0..1920
  const int wm = (w >> 1) * 64, wn = (w & 1) * 64;
  const f32x4 fz = {0.f, 0.f, 0.f, 0.f};
  __hip_bfloat16* Cd = (n0 < HID_) ? C0 : C1;
  const int nofs = (n0 < HID_) ? 0 : HID_;

  f32x4 acc[4][4];
#pragma unroll
  for (int i = 0; i < 4; i++)
#pragma unroll
    for (int j = 0; j < 4; j++) acc[i][j] = fz;

  for (int kk = 0; kk < HID_ / 32; kk++) {
    const int k0 = kk * 32;
    __syncthreads();
#pragma unroll
    for (int t = 0; t < 2; t++) {
      int c = (w * 2 + t) * 64 + lane;
      int row = c >> 2;
      int cid = (c & 3) ^ (row & 3);
      async_copy16(A + (size_t)(m0 + row) * HID_ + k0 + cid * 8, (char*)sA + c * 16);
      async_copy16(BT + (size_t)(n0 + row) * HID_ + k0 + cid * 8, (char*)sB + c * 16);
    }
    __syncthreads();
    short8 af[4], bf[4];
#pragma unroll
    for (int mt = 0; mt < 4; mt++) {
      int r = wm + mt * 16 + l16;
      af[mt] = *(const short8*)((const char*)sA + r * 64 + ((quad ^ (r & 3)) * 16));
    }
#pragma unroll
    for (int nt = 0; nt < 4; nt++) {
      int r = wn + nt * 16 + l16;
      bf[nt] = *(const short8*)((const char*)sB + r * 64 + ((quad ^ (r & 3)) * 16));
    }
#pragma unroll
    for (int mt = 0; mt < 4; mt++)
#pragma unroll
      for (int nt = 0; nt < 4; nt++)
        acc[mt][nt] = __builtin_amdgcn_mfma_f32_16x16x32_bf16(af[mt], bf[nt], acc[mt][nt], 0, 0, 0);
  }
#pragma unroll
  for (int mt = 0; mt < 4; mt++)
#pragma unroll
    for (int nt = 0; nt < 4; nt++)
#pragma unroll
      for (int rg = 0; rg < 4; rg++) {
        int r = m0 + wm + mt * 16 + quad * 4 + rg;
        int cc = n0 + wn + nt * 16 + l16 - nofs;
        Cd[(size_t)r * HID_ + cc] = __float2bfloat16(acc[mt][nt][rg]);
      }
}

// ---------------- fused bias dots (pre-scaled by log2e/64): cb then eb ----------------
__global__ __launch_bounds__(256) void bias_kernel(const __hip_bfloat16* __restrict__ kp,
                                                   const __hip_bfloat16* __restrict__ relp,
                                                   const void* __restrict__ rwb,
                                                   const void* __restrict__ rrb,
                                                   float* __restrict__ cb,
                                                   float* __restrict__ eb,
                                                   const int* __restrict__ mode) {
  const int md = *mode;
  int idx = blockIdx.x * 256 + threadIdx.x;
  const __hip_bfloat16* row;
  const void* bias;
  float* out;
  int h;
  if (idx < NCB) {
    const int j = idx % KL_;
    h = (idx / KL_) % H_;
    const int b = idx / (KL_ * H_);
    row = kp + ((size_t)b * KL_ + j) * HID_ + h * D_;
    bias = rwb; out = cb + idx;
  } else {
    idx -= NCB;
    if (idx >= NEB) return;
    const int p = idx % (KL_ + EPAD);
    h = idx / (KL_ + EPAD);
    const int pc = p < KL_ ? p : KL_ - 1;          // pad rows: finite junk (masked downstream)
    row = relp + (size_t)pc * HID_ + h * D_;
    bias = rrb; out = eb + idx;
  }
  float s = 0.f;
#pragma unroll
  for (int t = 0; t < 8; t++) {
    short8 v = *(const short8*)(row + t * 8);
#pragma unroll
    for (int u = 0; u < 8; u++) {
      short sb = v[u];
      s += __bfloat162float(*(__hip_bfloat16*)&sb) * ldin(bias, h * D_ + t * 8 + u, md);
    }
  }
  *out = s * LSCL;
}

// ---------------- fused relative attention (R5 structure + log2 folding) ----------------
// grid 1024 flat (XCD-remapped), block 256 (4 waves). Logits in log2 units. K+rel+V^T all
// DMA-staged between barriers A and B (one drain per tile). sTP rows stride 304 B
// (measured-best bank behavior). 75 KB LDS -> 2 blocks/CU.
__global__ __launch_bounds__(256, 2) void attn_kernel(
    const __hip_bfloat16* __restrict__ qp, const __hip_bfloat16* __restrict__ kp,
    const __hip_bfloat16* __restrict__ vpt, const __hip_bfloat16* __restrict__ relp,
    const float* __restrict__ cb, const float* __restrict__ eb,
    const void* __restrict__ spanv, __hip_bfloat16* __restrict__ attn_out,
    const int* __restrict__ mode) {
  const int md = *mode;
  const int bid = blockIdx.x;
  const int bh = (bid & 7) + 8 * (bid >> 8);
  const int i0 = ((bid >> 3) & 31) * RT_;
  const int b = bh >> 4, h = bh & 15;

  const int tid = threadIdx.x;
  const int lane = tid & 63;
  const int w = tid >> 6;
  const int quad = lane >> 4, l16 = lane & 15;
  const int di = w * 16 + l16;        // this thread's softmax row (block-local)
  const int iRow = i0 + di;
  const f32x4 fz = {0.f, 0.f, 0.f, 0.f};

  __shared__ __attribute__((aligned(16))) __hip_bfloat16 sk[128 * 64];    // 16 KB K tile (q staged here first)
  __shared__ __attribute__((aligned(16))) __hip_bfloat16 srel[192 * 64];  // 24 KB rel band
  __shared__ __attribute__((aligned(16))) __hip_bfloat16 svt[64 * 128];   // 16 KB V^T tile
  __shared__ __attribute__((aligned(16))) short sTP[64 * 152];            // 19 KB T-band/P rows

  const int rb = di * 304;            // private row base (bytes), 16B-aligned

  const __hip_bfloat16* kbase = kp + (size_t)b * KL_ * HID_ + h * D_;
  const __hip_bfloat16* vtb = vpt + ((size_t)(b * H_ + h)) * D_ * KL_;
  const float* cbb = cb + (size_t)(b * H_ + h) * KL_;
  const float* ebb = eb + (size_t)h * (KL_ + EPAD);
  const float sv = ldin(spanv, h, md);
  const float svQ = sv * (float)Q_;
  const int pb0 = Q_ - RT_ - i0;
  const int wof = (3 - w) * 16;       // this wave's T-band p-window offset
  const int ntiles = ((M_ + i0 + RT_ - 1) >> 7) + 1;

  // ---- stage q once via sk, read own-row B-fragments ----
  {
    const __hip_bfloat16* qb = qp + ((size_t)(b * Q_ + i0)) * HID_ + h * D_;
#pragma unroll
    for (int t = 0; t < 2; t++) {
      int c = (w * 2 + t) * 64 + lane;
      int row = c >> 3;
      int cid = (c & 7) ^ (row & 7);
      async_copy16(qb + (size_t)row * HID_ + cid * 8, (char*)sk + c * 16);
    }
  }
  __syncthreads();
  short8 qf[2];
#pragma unroll
  for (int ks = 0; ks < 2; ks++)
    qf[ks] = *(const short8*)((const char*)sk + di * 128 + (((ks * 4 + quad) ^ (di & 7)) * 16));

  float mrow = -3e38f, lrow = 0.f, dfrow = 0.f;
  f32x4 oacc[4];
#pragma unroll
  for (int dt = 0; dt < 4; dt++) oacc[dt] = fz;

  for (int kt = 0; kt < ntiles; kt++) {
    const int j0 = kt * WT_;
    const int pbase = pb0 + j0;

    __syncthreads();  // A: prior tile's LDS consumers done (and q-frag reads, tile 0)
    // ---- DMA staging: K (4), rel band (6), V^T (4) ----
#pragma unroll
    for (int t = 0; t < 4; t++) {
      int c = (w * 4 + t) * 64 + lane;
      int row = c >> 3;
      int cid = (c & 7) ^ (row & 7);
      async_copy16(kbase + (size_t)(j0 + row) * HID_ + cid * 8, (char*)sk + c * 16);
    }
#pragma unroll
    for (int t = 0; t < 6; t++) {
      int c = (w * 6 + t) * 64 + lane;
      int row = c >> 3;
      int cid = (c & 7) ^ (row & 7);
      int p = pbase + row; p = p < KL_ ? p : KL_ - 1;  // clamped rows feed only masked cols
      async_copy16(relp + (size_t)p * HID_ + h * D_ + cid * 8, (char*)srel + c * 16);
    }
#pragma unroll
    for (int t = 0; t < 4; t++) {
      int c = (w * 4 + t) * 64 + lane;
      int row = c >> 4;
      int cid = (c & 15) ^ (row & 15);
      async_copy16(vtb + (size_t)row * KL_ + j0 + cid * 8, (char*)svt + c * 16);
    }
    __syncthreads();  // B: DMA drained

    // ---- S^T[j][i] = K . Q^T ----
    f32x4 S[8];
#pragma unroll
    for (int mt = 0; mt < 8; mt++) S[mt] = fz;
#pragma unroll
    for (int mt = 0; mt < 8; mt++) {
      int r = mt * 16 + l16;
#pragma unroll
      for (int ks = 0; ks < 2; ks++) {
        short8 af = *(const short8*)((const char*)sk + r * 128 + (((ks * 4 + quad) ^ (r & 7)) * 16));
        S[mt] = __builtin_amdgcn_mfma_f32_16x16x32_bf16(af, qf[ks], S[mt], 0, 0, 0);
      }
    }

    // ---- T band (wave's 144-col window), +e, store into own sTP row ----
#pragma unroll
    for (int mt = 0; mt < 9; mt++) {
      f32x4 T = fz;
      int r = wof + mt * 16 + l16;
#pragma unroll
      for (int ks = 0; ks < 2; ks++) {
        short8 af = *(const short8*)((const char*)srel + r * 128 + (((ks * 4 + quad) ^ (r & 7)) * 16));
        T = __builtin_amdgcn_mfma_f32_16x16x32_bf16(af, qf[ks], T, 0, 0, 0);
      }
      const int lo = mt * 16 + quad * 4;              // local band offset [0,144)
      f32x4 e4 = *(const f32x4*)(ebb + pbase + wof + lo);
      short4v pk;
#pragma unroll
      for (int rg = 0; rg < 4; rg++) pk[rg] = bfbits(T[rg] + e4[rg]);
      *(short4v*)((char*)sTP + rb + lo * 2) = pk;
    }

    // ---- gather with per-row shift (own row, in-order DS) ----
#pragma unroll
    for (int mt = 0; mt < 8; mt++)
#pragma unroll
      for (int rg = 0; rg < 4; rg++) {
        int tcl = 15 - l16 + mt * 16 + quad * 4 + rg;
        S[mt][rg] += __bfloat162float(*(const __hip_bfloat16*)((const char*)sTP + rb + tcl * 2));
      }

    // ---- logits (log2 units), causal mask only on tiles that can need it ----
    const bool causalT = (j0 + WT_ - 1 - i0) > M_;
    float mnew = mrow;
#pragma unroll
    for (int mt = 0; mt < 8; mt++) {
      f32x4 cb4 = *(const f32x4*)(cbb + j0 + mt * 16 + quad * 4);
#pragma unroll
      for (int rg = 0; rg < 4; rg++) {
        float v = S[mt][rg] + cb4[rg];
        if (causalT) {
          int j = j0 + mt * 16 + quad * 4 + rg;
          if (j - iRow > M_) v = -1e30f;
        }
        S[mt][rg] = v;
        mnew = fmaxf(mnew, v);
      }
    }
    mnew = fmaxf(mnew, __shfl_xor(mnew, 16));
    mnew = fmaxf(mnew, __shfl_xor(mnew, 32));
    const float alpha = fexp2(mrow - mnew);
    mrow = mnew;
    lrow *= alpha; dfrow *= alpha;
    float aR[4];
#pragma unroll
    for (int rg = 0; rg < 4; rg++) aR[rg] = __shfl(alpha, quad * 4 + rg);
#pragma unroll
    for (int dt = 0; dt < 4; dt++)
#pragma unroll
      for (int rg = 0; rg < 4; rg++) oacc[dt][rg] *= aR[rg];

    // ---- P = exp2(S-m); span deficit only on tiles overlapping the ramp ----
    const bool maskT = (j0 + WT_ > M_) && ((float)j0 < (float)M_ + 33.f - svQ);
#pragma unroll
    for (int mt = 0; mt < 8; mt++) {
      short4v pk;
#pragma unroll
      for (int rg = 0; rg < 4; rg++) {
        float pv = fexp2(S[mt][rg] - mrow);
        lrow += pv;
        float pm = pv;
        if (maskT) {
          int j = j0 + mt * 16 + quad * 4 + rg;
          if (j >= M_) {
            float t0 = (float)(j - M_) + svQ;
            float mk = fminf(fmaxf(t0 * (1.0f / 33.0f), 0.f), 1.f);
            pm = pv * mk;
            dfrow += pv - pm;
          }
        }
        pk[rg] = bfbits(pm);
      }
      *(short4v*)((char*)sTP + rb + (mt * 16 + quad * 4) * 2) = pk;
    }

    // ---- PV: A = P (own rows, b128 from sTP), B = V^T rows from svt ----
#pragma unroll
    for (int ks = 0; ks < 4; ks++) {
      short8 af = *(const short8*)((const char*)sTP + rb + ks * 64 + quad * 16);
#pragma unroll
      for (int dt = 0; dt < 4; dt++) {
        int r = dt * 16 + l16;
        short8 bfv = *(const short8*)((const char*)svt + r * 256 + (((ks * 4 + quad) ^ (r & 15)) * 16));
        oacc[dt] = __builtin_amdgcn_mfma_f32_16x16x32_bf16(af, bfv, oacc[dt], 0, 0, 0);
      }
    }
  }

  // ---- epilogue: lm = lr - deficit ----
  lrow += __shfl_xor(lrow, 16);  lrow += __shfl_xor(lrow, 32);
  dfrow += __shfl_xor(dfrow, 16); dfrow += __shfl_xor(dfrow, 32);
  float lr4[4], df4[4];
#pragma unroll
  for (int rg = 0; rg < 4; rg++) {
    lr4[rg] = __shfl(lrow, quad * 4 + rg);
    df4[rg] = __shfl(dfrow, quad * 4 + rg);
  }
#pragma unroll
  for (int dt = 0; dt < 4; dt++)
#pragma unroll
    for (int rg = 0; rg < 4; rg++) {
      int i = i0 + w * 16 + quad * 4 + rg;
      float denom = (lr4[rg] - df4[rg]) + 1e-8f * lr4[rg];
      float ov = oacc[dt][rg] / denom;
      attn_out[((size_t)(b * Q_ + i)) * HID_ + h * D_ + dt * 16 + l16] = __float2bfloat16(ov);
    }
}

// ---------------- launcher ----------------
extern "C" void kernel_launch(void* const* d_in, const int* in_sizes, int n_in,
                              void* d_out, int out_size, void* d_ws, size_t ws_size,
                              hipStream_t stream) {
  const void* query  = d_in[0];
  const void* memory = d_in[1];
  const void* Wq = d_in[2];
  const void* Wk = d_in[3];
  const void* Wv = d_in[4];
  const void* Wo = d_in[5];
  const void* Wr = d_in[6];
  const void* gmem = d_in[7];
  const void* bmem = d_in[8];
  const void* gq = d_in[9];
  const void* bq = d_in[10];
  const void* rwb = d_in[11];
  const void* rrb = d_in[12];
  const void* spanv = d_in[13];

  char* ws = (char*)d_ws;
  size_t off = 0;
  auto alloc = [&](size_t bytes) -> char* {
    char* p = ws + off;
    off += (bytes + 255) & ~(size_t)255;
    return p;
  };
  int* flag = (int*)alloc(256);
  const size_t SZ_W = (size_t)HID_ * HID_ * 2;
  __hip_bfloat16* wqT = (__hip_bfloat16*)alloc(SZ_W);
  __hip_bfloat16* wkT = (__hip_bfloat16*)alloc(SZ_W);   // contiguous with wvT (SZ_W is 256B-aligned)
  __hip_bfloat16* wvT = (__hip_bfloat16*)alloc(SZ_W);
  __hip_bfloat16* wrT = (__hip_bfloat16*)alloc(SZ_W);
  __hip_bfloat16* woT = (__hip_bfloat16*)alloc(SZ_W);
  __hip_bfloat16* kvln = (__hip_bfloat16*)alloc((size_t)B_ * KL_ * HID_ * 2);
  __hip_bfloat16* qln  = (__hip_bfloat16*)alloc((size_t)B_ * Q_ * HID_ * 2);
  __hip_bfloat16* pe   = (__hip_bfloat16*)alloc((size_t)KL_ * HID_ * 2);
  __hip_bfloat16* qpb  = (__hip_bfloat16*)alloc((size_t)B_ * Q_ * HID_ * 2);
  __hip_bfloat16* kpb  = (__hip_bfloat16*)alloc((size_t)B_ * KL_ * HID_ * 2);
  __hip_bfloat16* vpb  = (__hip_bfloat16*)alloc((size_t)B_ * KL_ * HID_ * 2);
  __hip_bfloat16* relp = (__hip_bfloat16*)alloc((size_t)KL_ * HID_ * 2);
  __hip_bfloat16* aout = (__hip_bfloat16*)alloc((size_t)B_ * Q_ * HID_ * 2);
  float* cbf = (float*)alloc((size_t)NCB * 4);
  float* ebf = (float*)alloc((size_t)NEB * 4);
  __hip_bfloat16* vptb = kvln;  // alias: kvln dead after the k/v projection GEMMs

  dim3 tb(256);
  detect_kernel<<<dim3(1), tb, 0, stream>>>((const unsigned int*)query, flag);

  wt5_kernel<<<dim3(16, 16, 5), tb, 0, stream>>>(Wq, Wk, Wv, Wr, Wo,
                                                 wqT, wkT, wvT, wrT, woT, flag);

  ln_kv_kernel<<<dim3(B_ * KL_), tb, 0, stream>>>(memory, query, gmem, bmem, kvln, flag);
  ln_q_kernel<<<dim3(B_ * Q_), tb, 0, stream>>>(query, gq, bq, qln, flag);
  posemb_kernel<<<dim3(KL_), tb, 0, stream>>>(pe);

  gemm_bt128<<<dim3(B_ * Q_ / 128, HID_ / 128), tb, 0, stream>>>(qln, wqT, qpb, LSCL);
  gemm_dual<<<dim3(B_ * KL_ / 128, 2 * HID_ / 128), tb, 0, stream>>>(kvln, wkT, kpb, vpb);
  gemm_bt128<<<dim3(KL_ / 128, HID_ / 128), tb, 0, stream>>>(pe, wrT, relp, 1.0f);

  vpt_kernel<<<dim3(KL_ / 64, B_ * H_), tb, 0, stream>>>(vpb, vptb);
  bias_kernel<<<dim3((NCB + NEB + 255) / 256), tb, 0, stream>>>(kpb, relp, rwb, rrb, cbf, ebf, flag);

  attn_kernel<<<dim3((Q_ / RT_) * H_ * B_), tb, 0, stream>>>(qpb, kpb, vptb, relp, cbf, ebf, spanv, aout, flag);

  gemm_out<<<dim3(B_ * Q_ / 128, HID_ / 128), tb, 0, stream>>>(aout, woT, d_out, flag);

  (void)in_sizes; (void)n_in; (void)out_size; (void)ws_size;
}

// Round 11
// 583.614 us; speedup vs baseline: 1.3766x; 1.0383x over previous
//
#include <hip/hip_runtime.h>
#include <hip/hip_bf16.h>
#include <math.h>

#define B_   2
#define Q_   2048
#define M_   2048
#define H_   16
#define D_   64
#define HID_ 1024
#define KL_  4096
#define RT_  64      // q rows per attention block
#define WT_  128     // k cols per attention tile
#define LSCL 0.022542110013890053f   // log2(e)/64 — logits kept in log2 units

typedef short short8 __attribute__((ext_vector_type(8)));
typedef short short4v __attribute__((ext_vector_type(4)));
typedef float f32x4 __attribute__((ext_vector_type(4)));

__device__ __forceinline__ void async_copy16(const void* g, void* l) {
  __builtin_amdgcn_global_load_lds((const __attribute__((address_space(1))) unsigned int*)g,
                                   (__attribute__((address_space(3))) unsigned int*)l,
                                   16, 0, 0);
}

// read input element i as float, md=1 -> fp32 buffer, md=0 -> bf16 buffer
__device__ __forceinline__ float ldin(const void* p, size_t i, int md) {
  return md ? ((const float*)p)[i] : __bfloat162float(((const __hip_bfloat16*)p)[i]);
}

__device__ __forceinline__ short bfbits(float v) {
  __hip_bfloat16 t = __float2bfloat16(v);
  return *(short*)&t;
}

// fast 2^x: lowers to v_exp_f32 (HW computes 2^x natively)
__device__ __forceinline__ float fexp2(float x) { return exp2f(x); }

// ---------------- dtype detector: writes 1 if inputs are fp32, else 0 ----------------
__global__ __launch_bounds__(256) void detect_kernel(const unsigned int* __restrict__ q,
                                                     int* __restrict__ flag) {
  __shared__ int cnt;
  if (threadIdx.x == 0) cnt = 0;
  __syncthreads();
  int ins = 0;
#pragma unroll
  for (int i = 0; i < 4; i++) {
    unsigned int u = q[threadIdx.x * 4 + i];
    int e0 = (int)((u >> 7) & 0xffu);
    int e1 = (int)((u >> 23) & 0xffu);
    if (e0 == 0xff || e0 < 102 || e0 > 140) ins++;
    if (e1 == 0xff || e1 < 102 || e1 > 140) ins++;
  }
  atomicAdd(&cnt, ins);
  __syncthreads();
  if (threadIdx.x == 0) *flag = (cnt > 512) ? 1 : 0;
}

// ---------------- fused weight transposes: wt[n][k] = src[k][n], 5 x 1024x1024 ----------------
__global__ __launch_bounds__(256) void wt5_kernel(
    const void* __restrict__ s0, const void* __restrict__ s1, const void* __restrict__ s2,
    const void* __restrict__ s3, const void* __restrict__ s4,
    __hip_bfloat16* __restrict__ d0, __hip_bfloat16* __restrict__ d1,
    __hip_bfloat16* __restrict__ d2, __hip_bfloat16* __restrict__ d3,
    __hip_bfloat16* __restrict__ d4, const int* __restrict__ mode) {
  const int md = *mode;
  const void* src; __hip_bfloat16* dst;
  switch (blockIdx.z) {
    case 0: src = s0; dst = d0; break;
    case 1: src = s1; dst = d1; break;
    case 2: src = s2; dst = d2; break;
    case 3: src = s3; dst = d3; break;
    default: src = s4; dst = d4; break;
  }
  const int r0 = blockIdx.x * 64, c0 = blockIdx.y * 64;
  __shared__ __hip_bfloat16 t[64][65];
  const int tid = threadIdx.x;
  const int col = tid & 63, r4 = tid >> 6;
#pragma unroll
  for (int i = 0; i < 16; i++)
    t[r4 + i * 4][col] = __float2bfloat16(ldin(src, (size_t)(r0 + r4 + i * 4) * HID_ + c0 + col, md));
  __syncthreads();
#pragma unroll
  for (int i = 0; i < 16; i++)
    dst[(size_t)(c0 + r4 + i * 4) * HID_ + r0 + col] = t[col][r4 + i * 4];
}

// ---------------- V transpose: vpt[b][h][d][j] = vp[b*K+j][h*64+d] ----------------
__global__ __launch_bounds__(256) void vpt_kernel(const __hip_bfloat16* __restrict__ vp,
                                                  __hip_bfloat16* __restrict__ vpt) {
  const int jt = blockIdx.x * 64;
  const int bh = blockIdx.y;
  const int b = bh / H_, h = bh % H_;
  __shared__ __hip_bfloat16 t[64][65];
  const int tid = threadIdx.x;
  const int col = tid & 63, r4 = tid >> 6;
#pragma unroll
  for (int i = 0; i < 16; i++) {
    int j = r4 + i * 4;
    t[j][col] = vp[((size_t)b * KL_ + jt + j) * HID_ + h * D_ + col];
  }
  __syncthreads();
#pragma unroll
  for (int i = 0; i < 16; i++) {
    int d = r4 + i * 4;
    vpt[(((size_t)b * H_ + h) * D_ + d) * KL_ + jt + col] = t[col][d];
  }
}

// ---------------- LayerNorm over concat(memory, query) rows ----------------
__global__ __launch_bounds__(256) void ln_kv_kernel(
    const void* __restrict__ mem, const void* __restrict__ qry,
    const void* __restrict__ gamma, const void* __restrict__ beta,
    __hip_bfloat16* __restrict__ out, const int* __restrict__ mode) {
  const int md = *mode;
  const int row = blockIdx.x;  // 0..B*KL-1
  const int b = row / KL_, j = row % KL_;
  const void* src;
  size_t base;
  if (j < M_) { src = mem; base = ((size_t)b * M_ + j) * HID_; }
  else        { src = qry; base = ((size_t)b * Q_ + (j - M_)) * HID_; }
  const int tid = threadIdx.x;
  float x[4];
  float s = 0.f, ss = 0.f;
#pragma unroll
  for (int i = 0; i < 4; i++) {
    x[i] = ldin(src, base + i * 256 + tid, md);
    s += x[i]; ss += x[i] * x[i];
  }
#pragma unroll
  for (int o = 32; o > 0; o >>= 1) { s += __shfl_down(s, o); ss += __shfl_down(ss, o); }
  __shared__ float red[8];
  if ((tid & 63) == 0) { red[(tid >> 6) * 2] = s; red[(tid >> 6) * 2 + 1] = ss; }
  __syncthreads();
  float ts = 0.f, tss = 0.f;
#pragma unroll
  for (int i = 0; i < 4; i++) { ts += red[i * 2]; tss += red[i * 2 + 1]; }
  const float mu = ts * (1.f / 1024.f);
  const float var = tss * (1.f / 1024.f) - mu * mu;
  const float rs = rsqrtf(var + 1e-3f);
  __hip_bfloat16* dst = out + (size_t)row * HID_;
#pragma unroll
  for (int i = 0; i < 4; i++) {
    int c = i * 256 + tid;
    dst[c] = __float2bfloat16((x[i] - mu) * rs * ldin(gamma, c, md) + ldin(beta, c, md));
  }
}

__global__ __launch_bounds__(256) void ln_q_kernel(
    const void* __restrict__ qry,
    const void* __restrict__ gamma, const void* __restrict__ beta,
    __hip_bfloat16* __restrict__ out, const int* __restrict__ mode) {
  const int md = *mode;
  const int row = blockIdx.x;  // 0..B*Q-1
  const size_t base = (size_t)row * HID_;
  const int tid = threadIdx.x;
  float x[4];
  float s = 0.f, ss = 0.f;
#pragma unroll
  for (int i = 0; i < 4; i++) {
    x[i] = ldin(qry, base + i * 256 + tid, md);
    s += x[i]; ss += x[i] * x[i];
  }
#pragma unroll
  for (int o = 32; o > 0; o >>= 1) { s += __shfl_down(s, o); ss += __shfl_down(ss, o); }
  __shared__ float red[8];
  if ((tid & 63) == 0) { red[(tid >> 6) * 2] = s; red[(tid >> 6) * 2 + 1] = ss; }
  __syncthreads();
  float ts = 0.f, tss = 0.f;
#pragma unroll
  for (int i = 0; i < 4; i++) { ts += red[i * 2]; tss += red[i * 2 + 1]; }
  const float mu = ts * (1.f / 1024.f);
  const float var = tss * (1.f / 1024.f) - mu * mu;
  const float rs = rsqrtf(var + 1e-3f);
  __hip_bfloat16* dst = out + (size_t)row * HID_;
#pragma unroll
  for (int i = 0; i < 4; i++) {
    int c = i * 256 + tid;
    dst[c] = __float2bfloat16((x[i] - mu) * rs * ldin(gamma, c, md) + ldin(beta, c, md));
  }
}

// ---------------- sinusoidal position embedding, positions K-1..0 ----------------
__global__ __launch_bounds__(256) void posemb_kernel(__hip_bfloat16* __restrict__ pe) {
  const int p = blockIdx.x;
  const float pos = (float)(KL_ - 1 - p);
  const int tid = threadIdx.x;
#pragma unroll
  for (int i = 0; i < 4; i++) {
    int c = tid * 4 + i;
    int f = (c < 512) ? c : c - 512;
    float invf = fexp2(-(float)f * (13.287712379549449f / 512.0f));
    float a = pos * invf;
    float v = (c < 512) ? __sinf(a) : __cosf(a);
    pe[(size_t)p * HID_ + c] = __float2bfloat16(v);
  }
}

// ---------------- GEMM core: C = A @ BT^T (both bf16, K=1024), 128x128 tile ----------------
template <int WRITE_MODE_SWITCH>
__device__ __forceinline__ void gemm_body(const __hip_bfloat16* __restrict__ A,
                                          const __hip_bfloat16* __restrict__ BT,
                                          void* __restrict__ C, int md, float scl) {
  __shared__ __attribute__((aligned(16))) __hip_bfloat16 sA[128 * 32];
  __shared__ __attribute__((aligned(16))) __hip_bfloat16 sB[128 * 32];
  const int tid = threadIdx.x;
  const int lane = tid & 63;
  const int w = tid >> 6;
  const int quad = lane >> 4, l16 = lane & 15;
  const int m0 = blockIdx.x * 128;
  const int n0 = blockIdx.y * 128;
  const int wm = (w >> 1) * 64, wn = (w & 1) * 64;
  const f32x4 fz = {0.f, 0.f, 0.f, 0.f};

  f32x4 acc[4][4];
#pragma unroll
  for (int i = 0; i < 4; i++)
#pragma unroll
    for (int j = 0; j < 4; j++) acc[i][j] = fz;

  for (int kk = 0; kk < HID_ / 32; kk++) {
    const int k0 = kk * 32;
    __syncthreads();
#pragma unroll
    for (int t = 0; t < 2; t++) {
      int c = (w * 2 + t) * 64 + lane;
      int row = c >> 2;
      int cid = (c & 3) ^ (row & 3);
      async_copy16(A + (size_t)(m0 + row) * HID_ + k0 + cid * 8, (char*)sA + c * 16);
      async_copy16(BT + (size_t)(n0 + row) * HID_ + k0 + cid * 8, (char*)sB + c * 16);
    }
    __syncthreads();
    short8 af[4], bf[4];
#pragma unroll
    for (int mt = 0; mt < 4; mt++) {
      int r = wm + mt * 16 + l16;
      af[mt] = *(const short8*)((const char*)sA + r * 64 + ((quad ^ (r & 3)) * 16));
    }
#pragma unroll
    for (int nt = 0; nt < 4; nt++) {
      int r = wn + nt * 16 + l16;
      bf[nt] = *(const short8*)((const char*)sB + r * 64 + ((quad ^ (r & 3)) * 16));
    }
#pragma unroll
    for (int mt = 0; mt < 4; mt++)
#pragma unroll
      for (int nt = 0; nt < 4; nt++)
        acc[mt][nt] = __builtin_amdgcn_mfma_f32_16x16x32_bf16(af[mt], bf[nt], acc[mt][nt], 0, 0, 0);
  }
#pragma unroll
  for (int mt = 0; mt < 4; mt++)
#pragma unroll
    for (int nt = 0; nt < 4; nt++)
#pragma unroll
      for (int rg = 0; rg < 4; rg++) {
        int r = m0 + wm + mt * 16 + quad * 4 + rg;
        int cc = n0 + wn + nt * 16 + l16;
        size_t idx = (size_t)r * HID_ + cc;
        if (WRITE_MODE_SWITCH && md) ((float*)C)[idx] = acc[mt][nt][rg];
        else ((__hip_bfloat16*)C)[idx] = __float2bfloat16(acc[mt][nt][rg] * scl);
      }
}

__global__ __launch_bounds__(256) void gemm_bt128(const __hip_bfloat16* __restrict__ A,
                                                  const __hip_bfloat16* __restrict__ BT,
                                                  __hip_bfloat16* __restrict__ C, float scl) {
  gemm_body<0>(A, BT, (void*)C, 0, scl);
}

__global__ __launch_bounds__(256) void gemm_out(const __hip_bfloat16* __restrict__ A,
                                                const __hip_bfloat16* __restrict__ BT,
                                                void* __restrict__ C,
                                                const int* __restrict__ mode) {
  gemm_body<1>(A, BT, C, *mode, 1.0f);
}

// ---- q-projection GEMM with dual-bias epilogue: qw=(acc+rwb)*LSCL, qr=(acc+rrb)*LSCL ----
__global__ __launch_bounds__(256) void gemm_q(const __hip_bfloat16* __restrict__ A,
                                              const __hip_bfloat16* __restrict__ BT,
                                              const void* __restrict__ rwb,
                                              const void* __restrict__ rrb,
                                              __hip_bfloat16* __restrict__ qw,
                                              __hip_bfloat16* __restrict__ qr,
                                              const int* __restrict__ mode) {
  const int md = *mode;
  __shared__ __attribute__((aligned(16))) __hip_bfloat16 sA[128 * 32];
  __shared__ __attribute__((aligned(16))) __hip_bfloat16 sB[128 * 32];
  const int tid = threadIdx.x;
  const int lane = tid & 63;
  const int w = tid >> 6;
  const int quad = lane >> 4, l16 = lane & 15;
  const int m0 = blockIdx.x * 128;
  const int n0 = blockIdx.y * 128;
  const int wm = (w >> 1) * 64, wn = (w & 1) * 64;
  const f32x4 fz = {0.f, 0.f, 0.f, 0.f};

  f32x4 acc[4][4];
#pragma unroll
  for (int i = 0; i < 4; i++)
#pragma unroll
    for (int j = 0; j < 4; j++) acc[i][j] = fz;

  for (int kk = 0; kk < HID_ / 32; kk++) {
    const int k0 = kk * 32;
    __syncthreads();
#pragma unroll
    for (int t = 0; t < 2; t++) {
      int c = (w * 2 + t) * 64 + lane;
      int row = c >> 2;
      int cid = (c & 3) ^ (row & 3);
      async_copy16(A + (size_t)(m0 + row) * HID_ + k0 + cid * 8, (char*)sA + c * 16);
      async_copy16(BT + (size_t)(n0 + row) * HID_ + k0 + cid * 8, (char*)sB + c * 16);
    }
    __syncthreads();
    short8 af[4], bf[4];
#pragma unroll
    for (int mt = 0; mt < 4; mt++) {
      int r = wm + mt * 16 + l16;
      af[mt] = *(const short8*)((const char*)sA + r * 64 + ((quad ^ (r & 3)) * 16));
    }
#pragma unroll
    for (int nt = 0; nt < 4; nt++) {
      int r = wn + nt * 16 + l16;
      bf[nt] = *(const short8*)((const char*)sB + r * 64 + ((quad ^ (r & 3)) * 16));
    }
#pragma unroll
    for (int mt = 0; mt < 4; mt++)
#pragma unroll
      for (int nt = 0; nt < 4; nt++)
        acc[mt][nt] = __builtin_amdgcn_mfma_f32_16x16x32_bf16(af[mt], bf[nt], acc[mt][nt], 0, 0, 0);
  }
  float bw[4], br[4];
#pragma unroll
  for (int nt = 0; nt < 4; nt++) {
    int cc = n0 + wn + nt * 16 + l16;
    bw[nt] = ldin(rwb, cc, md);
    br[nt] = ldin(rrb, cc, md);
  }
#pragma unroll
  for (int mt = 0; mt < 4; mt++)
#pragma unroll
    for (int nt = 0; nt < 4; nt++)
#pragma unroll
      for (int rg = 0; rg < 4; rg++) {
        int r = m0 + wm + mt * 16 + quad * 4 + rg;
        int cc = n0 + wn + nt * 16 + l16;
        size_t idx = (size_t)r * HID_ + cc;
        float a = acc[mt][nt][rg];
        qw[idx] = __float2bfloat16((a + bw[nt]) * LSCL);
        qr[idx] = __float2bfloat16((a + br[nt]) * LSCL);
      }
}

// ---- dual GEMM: BT is the contiguous [wkT; wvT] block (2048 rows); block-uniform output select ----
__global__ __launch_bounds__(256) void gemm_dual(const __hip_bfloat16* __restrict__ A,
                                                 const __hip_bfloat16* __restrict__ BT,
                                                 __hip_bfloat16* __restrict__ C0,
                                                 __hip_bfloat16* __restrict__ C1) {
  __shared__ __attribute__((aligned(16))) __hip_bfloat16 sA[128 * 32];
  __shared__ __attribute__((aligned(16))) __hip_bfloat16 sB[128 * 32];
  const int tid = threadIdx.x;
  const int lane = tid & 63;
  const int w = tid >> 6;
  const int quad = lane >> 4, l16 = lane & 15;
  const int m0 = blockIdx.x * 128;
  const int n0 = blockIdx.y * 128;  // 0..1920
  const int wm = (w >> 1) * 64, wn = (w & 1) * 64;
  const f32x4 fz = {0.f, 0.f, 0.f, 0.f};
  __hip_bfloat16* Cd = (n0 < HID_) ? C0 : C1;
  const int nofs = (n0 < HID_) ? 0 : HID_;

  f32x4 acc[4][4];
#pragma unroll
  for (int i = 0; i < 4; i++)
#pragma unroll
    for (int j = 0; j < 4; j++) acc[i][j] = fz;

  for (int kk = 0; kk < HID_ / 32; kk++) {
    const int k0 = kk * 32;
    __syncthreads();
#pragma unroll
    for (int t = 0; t < 2; t++) {
      int c = (w * 2 + t) * 64 + lane;
      int row = c >> 2;
      int cid = (c & 3) ^ (row & 3);
      async_copy16(A + (size_t)(m0 + row) * HID_ + k0 + cid * 8, (char*)sA + c * 16);
      async_copy16(BT + (size_t)(n0 + row) * HID_ + k0 + cid * 8, (char*)sB + c * 16);
    }
    __syncthreads();
    short8 af[4], bf[4];
#pragma unroll
    for (int mt = 0; mt < 4; mt++) {
      int r = wm + mt * 16 + l16;
      af[mt] = *(const short8*)((const char*)sA + r * 64 + ((quad ^ (r & 3)) * 16));
    }
#pragma unroll
    for (int nt = 0; nt < 4; nt++) {
      int r = wn + nt * 16 + l16;
      bf[nt] = *(const short8*)((const char*)sB + r * 64 + ((quad ^ (r & 3)) * 16));
    }
#pragma unroll
    for (int mt = 0; mt < 4; mt++)
#pragma unroll
      for (int nt = 0; nt < 4; nt++)
        acc[mt][nt] = __builtin_amdgcn_mfma_f32_16x16x32_bf16(af[mt], bf[nt], acc[mt][nt], 0, 0, 0);
  }
#pragma unroll
  for (int mt = 0; mt < 4; mt++)
#pragma unroll
    for (int nt = 0; nt < 4; nt++)
#pragma unroll
      for (int rg = 0; rg < 4; rg++) {
        int r = m0 + wm + mt * 16 + quad * 4 + rg;
        int cc = n0 + wn + nt * 16 + l16 - nofs;
        Cd[(size_t)r * HID_ + cc] = __float2bfloat16(acc[mt][nt][rg]);
      }
}

// ---------------- fused relative attention (bias-folded q: no cb/eb tables) ----------------
// grid 1024 flat (XCD-remapped), block 256 (4 waves). Logits in log2 units via pre-scaled
// q' = (q+rwb)*LSCL (S-path) and q'' = (q+rrb)*LSCL (T-path). K+rel+V^T DMA-staged between
// barriers A and B. sTP rows stride 304 B. 75 KB LDS -> 2 blocks/CU.
__global__ __launch_bounds__(256, 2) void attn_kernel(
    const __hip_bfloat16* __restrict__ qpw, const __hip_bfloat16* __restrict__ qpr,
    const __hip_bfloat16* __restrict__ kp, const __hip_bfloat16* __restrict__ vpt,
    const __hip_bfloat16* __restrict__ relp,
    const void* __restrict__ spanv, __hip_bfloat16* __restrict__ attn_out,
    const int* __restrict__ mode) {
  const int md = *mode;
  const int bid = blockIdx.x;
  const int bh = (bid & 7) + 8 * (bid >> 8);
  const int i0 = ((bid >> 3) & 31) * RT_;
  const int b = bh >> 4, h = bh & 15;

  const int tid = threadIdx.x;
  const int lane = tid & 63;
  const int w = tid >> 6;
  const int quad = lane >> 4, l16 = lane & 15;
  const int di = w * 16 + l16;        // this thread's softmax row (block-local)
  const int iRow = i0 + di;
  const f32x4 fz = {0.f, 0.f, 0.f, 0.f};

  __shared__ __attribute__((aligned(16))) __hip_bfloat16 sk[128 * 64];    // 16 KB K tile (q' staged here first)
  __shared__ __attribute__((aligned(16))) __hip_bfloat16 srel[192 * 64];  // 24 KB rel band
  __shared__ __attribute__((aligned(16))) __hip_bfloat16 svt[64 * 128];   // 16 KB V^T tile (q'' staged here first)
  __shared__ __attribute__((aligned(16))) short sTP[64 * 152];            // 19 KB T-band/P rows

  const int rb = di * 304;            // private row base (bytes), 16B-aligned

  const __hip_bfloat16* kbase = kp + (size_t)b * KL_ * HID_ + h * D_;
  const __hip_bfloat16* vtb = vpt + ((size_t)(b * H_ + h)) * D_ * KL_;
  const float sv = ldin(spanv, h, md);
  const float svQ = sv * (float)Q_;
  const int pb0 = Q_ - RT_ - i0;
  const int wof = (3 - w) * 16;       // this wave's T-band p-window offset
  const int ntiles = ((M_ + i0 + RT_ - 1) >> 7) + 1;

  // ---- stage q' (sk) and q'' (svt) once; read own-row B-fragments ----
  {
    const size_t qofs = ((size_t)(b * Q_ + i0)) * HID_ + h * D_;
    const __hip_bfloat16* qb = qpw + qofs;
    const __hip_bfloat16* qb2 = qpr + qofs;
#pragma unroll
    for (int t = 0; t < 2; t++) {
      int c = (w * 2 + t) * 64 + lane;
      int row = c >> 3;
      int cid = (c & 7) ^ (row & 7);
      async_copy16(qb + (size_t)row * HID_ + cid * 8, (char*)sk + c * 16);
      async_copy16(qb2 + (size_t)row * HID_ + cid * 8, (char*)svt + c * 16);
    }
  }
  __syncthreads();
  short8 qf[2], qrf[2];
#pragma unroll
  for (int ks = 0; ks < 2; ks++) {
    const int cid = ((ks * 4 + quad) ^ (di & 7)) * 16;
    qf[ks]  = *(const short8*)((const char*)sk  + di * 128 + cid);
    qrf[ks] = *(const short8*)((const char*)svt + di * 128 + cid);
  }

  float mrow = -3e38f, lrow = 0.f, dfrow = 0.f;
  f32x4 oacc[4];
#pragma unroll
  for (int dt = 0; dt < 4; dt++) oacc[dt] = fz;

  for (int kt = 0; kt < ntiles; kt++) {
    const int j0 = kt * WT_;
    const int pbase = pb0 + j0;

    __syncthreads();  // A: prior tile's LDS consumers done (and q-frag reads, tile 0)
    // ---- DMA staging: K (4), rel band (6), V^T (4) ----
#pragma unroll
    for (int t = 0; t < 4; t++) {
      int c = (w * 4 + t) * 64 + lane;
      int row = c >> 3;
      int cid = (c & 7) ^ (row & 7);
      async_copy16(kbase + (size_t)(j0 + row) * HID_ + cid * 8, (char*)sk + c * 16);
    }
#pragma unroll
    for (int t = 0; t < 6; t++) {
      int c = (w * 6 + t) * 64 + lane;
      int row = c >> 3;
      int cid = (c & 7) ^ (row & 7);
      int p = pbase + row; p = p < KL_ ? p : KL_ - 1;  // clamped rows feed only masked cols
      async_copy16(relp + (size_t)p * HID_ + h * D_ + cid * 8, (char*)srel + c * 16);
    }
#pragma unroll
    for (int t = 0; t < 4; t++) {
      int c = (w * 4 + t) * 64 + lane;
      int row = c >> 4;
      int cid = (c & 15) ^ (row & 15);
      async_copy16(vtb + (size_t)row * KL_ + j0 + cid * 8, (char*)svt + c * 16);
    }
    __syncthreads();  // B: DMA drained

    // ---- S^T[j][i] = K . q'^T ----
    f32x4 S[8];
#pragma unroll
    for (int mt = 0; mt < 8; mt++) S[mt] = fz;
#pragma unroll
    for (int mt = 0; mt < 8; mt++) {
      int r = mt * 16 + l16;
#pragma unroll
      for (int ks = 0; ks < 2; ks++) {
        short8 af = *(const short8*)((const char*)sk + r * 128 + (((ks * 4 + quad) ^ (r & 7)) * 16));
        S[mt] = __builtin_amdgcn_mfma_f32_16x16x32_bf16(af, qf[ks], S[mt], 0, 0, 0);
      }
    }

    // ---- T band (wave's 144-col window) = rel . q''^T, store into own sTP row ----
#pragma unroll
    for (int mt = 0; mt < 9; mt++) {
      f32x4 T = fz;
      int r = wof + mt * 16 + l16;
#pragma unroll
      for (int ks = 0; ks < 2; ks++) {
        short8 af = *(const short8*)((const char*)srel + r * 128 + (((ks * 4 + quad) ^ (r & 7)) * 16));
        T = __builtin_amdgcn_mfma_f32_16x16x32_bf16(af, qrf[ks], T, 0, 0, 0);
      }
      const int lo = mt * 16 + quad * 4;              // local band offset [0,144)
      short4v pk;
#pragma unroll
      for (int rg = 0; rg < 4; rg++) pk[rg] = bfbits(T[rg]);
      *(short4v*)((char*)sTP + rb + lo * 2) = pk;
    }

    // ---- gather with per-row shift (own row, in-order DS) ----
#pragma unroll
    for (int mt = 0; mt < 8; mt++)
#pragma unroll
      for (int rg = 0; rg < 4; rg++) {
        int tcl = 15 - l16 + mt * 16 + quad * 4 + rg;
        S[mt][rg] += __bfloat162float(*(const __hip_bfloat16*)((const char*)sTP + rb + tcl * 2));
      }

    // ---- logits (log2 units), causal mask only on tiles that can need it ----
    const bool causalT = (j0 + WT_ - 1 - i0) > M_;
    float mnew = mrow;
#pragma unroll
    for (int mt = 0; mt < 8; mt++) {
#pragma unroll
      for (int rg = 0; rg < 4; rg++) {
        float v = S[mt][rg];
        if (causalT) {
          int j = j0 + mt * 16 + quad * 4 + rg;
          if (j - iRow > M_) v = -1e30f;
        }
        S[mt][rg] = v;
        mnew = fmaxf(mnew, v);
      }
    }
    mnew = fmaxf(mnew, __shfl_xor(mnew, 16));
    mnew = fmaxf(mnew, __shfl_xor(mnew, 32));
    const float alpha = fexp2(mrow - mnew);
    mrow = mnew;
    lrow *= alpha; dfrow *= alpha;
    float aR[4];
#pragma unroll
    for (int rg = 0; rg < 4; rg++) aR[rg] = __shfl(alpha, quad * 4 + rg);
#pragma unroll
    for (int dt = 0; dt < 4; dt++)
#pragma unroll
      for (int rg = 0; rg < 4; rg++) oacc[dt][rg] *= aR[rg];

    // ---- P = exp2(S-m); span deficit only on tiles overlapping the ramp ----
    const bool maskT = (j0 + WT_ > M_) && ((float)j0 < (float)M_ + 33.f - svQ);
#pragma unroll
    for (int mt = 0; mt < 8; mt++) {
      short4v pk;
#pragma unroll
      for (int rg = 0; rg < 4; rg++) {
        float pv = fexp2(S[mt][rg] - mrow);
        lrow += pv;
        float pm = pv;
        if (maskT) {
          int j = j0 + mt * 16 + quad * 4 + rg;
          if (j >= M_) {
            float t0 = (float)(j - M_) + svQ;
            float mk = fminf(fmaxf(t0 * (1.0f / 33.0f), 0.f), 1.f);
            pm = pv * mk;
            dfrow += pv - pm;
          }
        }
        pk[rg] = bfbits(pm);
      }
      *(short4v*)((char*)sTP + rb + (mt * 16 + quad * 4) * 2) = pk;
    }

    // ---- PV: A = P (own rows, b128 from sTP), B = V^T rows from svt ----
#pragma unroll
    for (int ks = 0; ks < 4; ks++) {
      short8 af = *(const short8*)((const char*)sTP + rb + ks * 64 + quad * 16);
#pragma unroll
      for (int dt = 0; dt < 4; dt++) {
        int r = dt * 16 + l16;
        short8 bfv = *(const short8*)((const char*)svt + r * 256 + (((ks * 4 + quad) ^ (r & 15)) * 16));
        oacc[dt] = __builtin_amdgcn_mfma_f32_16x16x32_bf16(af, bfv, oacc[dt], 0, 0, 0);
      }
    }
  }

  // ---- epilogue: lm = lr - deficit ----
  lrow += __shfl_xor(lrow, 16);  lrow += __shfl_xor(lrow, 32);
  dfrow += __shfl_xor(dfrow, 16); dfrow += __shfl_xor(dfrow, 32);
  float lr4[4], df4[4];
#pragma unroll
  for (int rg = 0; rg < 4; rg++) {
    lr4[rg] = __shfl(lrow, quad * 4 + rg);
    df4[rg] = __shfl(dfrow, quad * 4 + rg);
  }
#pragma unroll
  for (int dt = 0; dt < 4; dt++)
#pragma unroll
    for (int rg = 0; rg < 4; rg++) {
      int i = i0 + w * 16 + quad * 4 + rg;
      float denom = (lr4[rg] - df4[rg]) + 1e-8f * lr4[rg];
      float ov = oacc[dt][rg] / denom;
      attn_out[((size_t)(b * Q_ + i)) * HID_ + h * D_ + dt * 16 + l16] = __float2bfloat16(ov);
    }
}

// ---------------- launcher ----------------
extern "C" void kernel_launch(void* const* d_in, const int* in_sizes, int n_in,
                              void* d_out, int out_size, void* d_ws, size_t ws_size,
                              hipStream_t stream) {
  const void* query  = d_in[0];
  const void* memory = d_in[1];
  const void* Wq = d_in[2];
  const void* Wk = d_in[3];
  const void* Wv = d_in[4];
  const void* Wo = d_in[5];
  const void* Wr = d_in[6];
  const void* gmem = d_in[7];
  const void* bmem = d_in[8];
  const void* gq = d_in[9];
  const void* bq = d_in[10];
  const void* rwb = d_in[11];
  const void* rrb = d_in[12];
  const void* spanv = d_in[13];

  char* ws = (char*)d_ws;
  size_t off = 0;
  auto alloc = [&](size_t bytes) -> char* {
    char* p = ws + off;
    off += (bytes + 255) & ~(size_t)255;
    return p;
  };
  int* flag = (int*)alloc(256);
  const size_t SZ_W = (size_t)HID_ * HID_ * 2;
  __hip_bfloat16* wqT = (__hip_bfloat16*)alloc(SZ_W);
  __hip_bfloat16* wkT = (__hip_bfloat16*)alloc(SZ_W);   // contiguous with wvT (SZ_W is 256B-aligned)
  __hip_bfloat16* wvT = (__hip_bfloat16*)alloc(SZ_W);
  __hip_bfloat16* wrT = (__hip_bfloat16*)alloc(SZ_W);
  __hip_bfloat16* woT = (__hip_bfloat16*)alloc(SZ_W);
  __hip_bfloat16* kvln = (__hip_bfloat16*)alloc((size_t)B_ * KL_ * HID_ * 2);
  __hip_bfloat16* qln  = (__hip_bfloat16*)alloc((size_t)B_ * Q_ * HID_ * 2);
  __hip_bfloat16* pe   = (__hip_bfloat16*)alloc((size_t)KL_ * HID_ * 2);
  __hip_bfloat16* qpw  = (__hip_bfloat16*)alloc((size_t)B_ * Q_ * HID_ * 2);
  __hip_bfloat16* qpr  = (__hip_bfloat16*)alloc((size_t)B_ * Q_ * HID_ * 2);
  __hip_bfloat16* kpb  = (__hip_bfloat16*)alloc((size_t)B_ * KL_ * HID_ * 2);
  __hip_bfloat16* vpb  = (__hip_bfloat16*)alloc((size_t)B_ * KL_ * HID_ * 2);
  __hip_bfloat16* relp = (__hip_bfloat16*)alloc((size_t)KL_ * HID_ * 2);
  __hip_bfloat16* aout = (__hip_bfloat16*)alloc((size_t)B_ * Q_ * HID_ * 2);
  __hip_bfloat16* vptb = kvln;  // alias: kvln dead after the k/v projection GEMMs

  dim3 tb(256);
  detect_kernel<<<dim3(1), tb, 0, stream>>>((const unsigned int*)query, flag);

  wt5_kernel<<<dim3(16, 16, 5), tb, 0, stream>>>(Wq, Wk, Wv, Wr, Wo,
                                                 wqT, wkT, wvT, wrT, woT, flag);

  ln_kv_kernel<<<dim3(B_ * KL_), tb, 0, stream>>>(memory, query, gmem, bmem, kvln, flag);
  ln_q_kernel<<<dim3(B_ * Q_), tb, 0, stream>>>(query, gq, bq, qln, flag);
  posemb_kernel<<<dim3(KL_), tb, 0, stream>>>(pe);

  gemm_q<<<dim3(B_ * Q_ / 128, HID_ / 128), tb, 0, stream>>>(qln, wqT, rwb, rrb, qpw, qpr, flag);
  gemm_dual<<<dim3(B_ * KL_ / 128, 2 * HID_ / 128), tb, 0, stream>>>(kvln, wkT, kpb, vpb);
  gemm_bt128<<<dim3(KL_ / 128, HID_ / 128), tb, 0, stream>>>(pe, wrT, relp, 1.0f);

  vpt_kernel<<<dim3(KL_ / 64, B_ * H_), tb, 0, stream>>>(vpb, vptb);

  attn_kernel<<<dim3((Q_ / RT_) * H_ * B_), tb, 0, stream>>>(qpw, qpr, kpb, vptb, relp, spanv, aout, flag);

  gemm_out<<<dim3(B_ * Q_ / 128, HID_ / 128), tb, 0, stream>>>(aout, woT, d_out, flag);

  (void)in_sizes; (void)n_in; (void)out_size; (void)ws_size;
}

// Round 12
// 569.341 us; speedup vs baseline: 1.4111x; 1.0251x over previous
//
#include <hip/hip_runtime.h>
#include <hip/hip_bf16.h>
#include <math.h>

#define B_   2
#define Q_   2048
#define M_   2048
#define H_   16
#define D_   64
#define HID_ 1024
#define KL_  4096
#define RT_  64      // q rows per attention block
#define WT_  128     // k cols per attention tile
#define LSCL 0.022542110013890053f   // log2(e)/64 — logits kept in log2 units

typedef short short8 __attribute__((ext_vector_type(8)));
typedef short short4v __attribute__((ext_vector_type(4)));
typedef float f32x4 __attribute__((ext_vector_type(4)));

__device__ __forceinline__ void async_copy16(const void* g, void* l) {
  __builtin_amdgcn_global_load_lds((const __attribute__((address_space(1))) unsigned int*)g,
                                   (__attribute__((address_space(3))) unsigned int*)l,
                                   16, 0, 0);
}

// read input element i as float, md=1 -> fp32 buffer, md=0 -> bf16 buffer
__device__ __forceinline__ float ldin(const void* p, size_t i, int md) {
  return md ? ((const float*)p)[i] : __bfloat162float(((const __hip_bfloat16*)p)[i]);
}

__device__ __forceinline__ short bfbits(float v) {
  __hip_bfloat16 t = __float2bfloat16(v);
  return *(short*)&t;
}

// fast 2^x: lowers to v_exp_f32 (HW computes 2^x natively)
__device__ __forceinline__ float fexp2(float x) { return exp2f(x); }

// ---------------- dtype detector: writes 1 if inputs are fp32, else 0 ----------------
__global__ __launch_bounds__(256) void detect_kernel(const unsigned int* __restrict__ q,
                                                     int* __restrict__ flag) {
  __shared__ int cnt;
  if (threadIdx.x == 0) cnt = 0;
  __syncthreads();
  int ins = 0;
#pragma unroll
  for (int i = 0; i < 4; i++) {
    unsigned int u = q[threadIdx.x * 4 + i];
    int e0 = (int)((u >> 7) & 0xffu);
    int e1 = (int)((u >> 23) & 0xffu);
    if (e0 == 0xff || e0 < 102 || e0 > 140) ins++;
    if (e1 == 0xff || e1 < 102 || e1 > 140) ins++;
  }
  atomicAdd(&cnt, ins);
  __syncthreads();
  if (threadIdx.x == 0) *flag = (cnt > 512) ? 1 : 0;
}

// ---------------- fused: 5 weight transposes (z<5) + sinusoidal pos-emb (z>=5) ----------------
__global__ __launch_bounds__(256) void wtpe_kernel(
    const void* __restrict__ s0, const void* __restrict__ s1, const void* __restrict__ s2,
    const void* __restrict__ s3, const void* __restrict__ s4,
    __hip_bfloat16* __restrict__ d0, __hip_bfloat16* __restrict__ d1,
    __hip_bfloat16* __restrict__ d2, __hip_bfloat16* __restrict__ d3,
    __hip_bfloat16* __restrict__ d4, __hip_bfloat16* __restrict__ pe,
    const int* __restrict__ mode) {
  const int tid = threadIdx.x;
  if (blockIdx.z >= 5) {
    // pos-emb: positions K-1..0
    const int p = (blockIdx.z - 5) * 256 + blockIdx.y * 16 + blockIdx.x;
    const float pos = (float)(KL_ - 1 - p);
#pragma unroll
    for (int i = 0; i < 4; i++) {
      int c = tid * 4 + i;
      int f = (c < 512) ? c : c - 512;
      float invf = fexp2(-(float)f * (13.287712379549449f / 512.0f));
      float a = pos * invf;
      float v = (c < 512) ? __sinf(a) : __cosf(a);
      pe[(size_t)p * HID_ + c] = __float2bfloat16(v);
    }
    return;
  }
  const int md = *mode;
  const void* src; __hip_bfloat16* dst;
  switch (blockIdx.z) {
    case 0: src = s0; dst = d0; break;
    case 1: src = s1; dst = d1; break;
    case 2: src = s2; dst = d2; break;
    case 3: src = s3; dst = d3; break;
    default: src = s4; dst = d4; break;
  }
  const int r0 = blockIdx.x * 64, c0 = blockIdx.y * 64;
  __shared__ __hip_bfloat16 t[64][65];
  const int col = tid & 63, r4 = tid >> 6;
#pragma unroll
  for (int i = 0; i < 16; i++)
    t[r4 + i * 4][col] = __float2bfloat16(ldin(src, (size_t)(r0 + r4 + i * 4) * HID_ + c0 + col, md));
  __syncthreads();
#pragma unroll
  for (int i = 0; i < 16; i++)
    dst[(size_t)(c0 + r4 + i * 4) * HID_ + r0 + col] = t[col][r4 + i * 4];
}

// ---------------- fused LayerNorm: rows [0,B*KL) = concat(mem,query); rows >= B*KL = query ----------------
__global__ __launch_bounds__(256) void ln_kernel(
    const void* __restrict__ mem, const void* __restrict__ qry,
    const void* __restrict__ gmem, const void* __restrict__ bmem,
    const void* __restrict__ gq, const void* __restrict__ bq,
    __hip_bfloat16* __restrict__ kvout, __hip_bfloat16* __restrict__ qout,
    const int* __restrict__ mode) {
  const int md = *mode;
  const int row = blockIdx.x;  // 0..B*KL + B*Q - 1
  const void* src;
  const void* gamma; const void* beta;
  size_t base;
  __hip_bfloat16* dst;
  if (row < B_ * KL_) {
    const int b = row / KL_, j = row % KL_;
    if (j < M_) { src = mem; base = ((size_t)b * M_ + j) * HID_; }
    else        { src = qry; base = ((size_t)b * Q_ + (j - M_)) * HID_; }
    gamma = gmem; beta = bmem;
    dst = kvout + (size_t)row * HID_;
  } else {
    const int r = row - B_ * KL_;
    src = qry; base = (size_t)r * HID_;
    gamma = gq; beta = bq;
    dst = qout + (size_t)r * HID_;
  }
  const int tid = threadIdx.x;
  float x[4];
  float s = 0.f, ss = 0.f;
#pragma unroll
  for (int i = 0; i < 4; i++) {
    x[i] = ldin(src, base + i * 256 + tid, md);
    s += x[i]; ss += x[i] * x[i];
  }
#pragma unroll
  for (int o = 32; o > 0; o >>= 1) { s += __shfl_down(s, o); ss += __shfl_down(ss, o); }
  __shared__ float red[8];
  if ((tid & 63) == 0) { red[(tid >> 6) * 2] = s; red[(tid >> 6) * 2 + 1] = ss; }
  __syncthreads();
  float ts = 0.f, tss = 0.f;
#pragma unroll
  for (int i = 0; i < 4; i++) { ts += red[i * 2]; tss += red[i * 2 + 1]; }
  const float mu = ts * (1.f / 1024.f);
  const float var = tss * (1.f / 1024.f) - mu * mu;
  const float rs = rsqrtf(var + 1e-3f);
#pragma unroll
  for (int i = 0; i < 4; i++) {
    int c = i * 256 + tid;
    dst[c] = __float2bfloat16((x[i] - mu) * rs * ldin(gamma, c, md) + ldin(beta, c, md));
  }
}

// ---------------- GEMM core: C = A @ BT^T (both bf16, K=1024), 128x128 tile ----------------
template <int WRITE_MODE_SWITCH>
__device__ __forceinline__ void gemm_body(const __hip_bfloat16* __restrict__ A,
                                          const __hip_bfloat16* __restrict__ BT,
                                          void* __restrict__ C, int md, float scl) {
  __shared__ __attribute__((aligned(16))) __hip_bfloat16 sA[128 * 32];
  __shared__ __attribute__((aligned(16))) __hip_bfloat16 sB[128 * 32];
  const int tid = threadIdx.x;
  const int lane = tid & 63;
  const int w = tid >> 6;
  const int quad = lane >> 4, l16 = lane & 15;
  const int m0 = blockIdx.x * 128;
  const int n0 = blockIdx.y * 128;
  const int wm = (w >> 1) * 64, wn = (w & 1) * 64;
  const f32x4 fz = {0.f, 0.f, 0.f, 0.f};

  f32x4 acc[4][4];
#pragma unroll
  for (int i = 0; i < 4; i++)
#pragma unroll
    for (int j = 0; j < 4; j++) acc[i][j] = fz;

  for (int kk = 0; kk < HID_ / 32; kk++) {
    const int k0 = kk * 32;
    __syncthreads();
#pragma unroll
    for (int t = 0; t < 2; t++) {
      int c = (w * 2 + t) * 64 + lane;
      int row = c >> 2;
      int cid = (c & 3) ^ (row & 3);
      async_copy16(A + (size_t)(m0 + row) * HID_ + k0 + cid * 8, (char*)sA + c * 16);
      async_copy16(BT + (size_t)(n0 + row) * HID_ + k0 + cid * 8, (char*)sB + c * 16);
    }
    __syncthreads();
    short8 af[4], bf[4];
#pragma unroll
    for (int mt = 0; mt < 4; mt++) {
      int r = wm + mt * 16 + l16;
      af[mt] = *(const short8*)((const char*)sA + r * 64 + ((quad ^ (r & 3)) * 16));
    }
#pragma unroll
    for (int nt = 0; nt < 4; nt++) {
      int r = wn + nt * 16 + l16;
      bf[nt] = *(const short8*)((const char*)sB + r * 64 + ((quad ^ (r & 3)) * 16));
    }
#pragma unroll
    for (int mt = 0; mt < 4; mt++)
#pragma unroll
      for (int nt = 0; nt < 4; nt++)
        acc[mt][nt] = __builtin_amdgcn_mfma_f32_16x16x32_bf16(af[mt], bf[nt], acc[mt][nt], 0, 0, 0);
  }
#pragma unroll
  for (int mt = 0; mt < 4; mt++)
#pragma unroll
    for (int nt = 0; nt < 4; nt++)
#pragma unroll
      for (int rg = 0; rg < 4; rg++) {
        int r = m0 + wm + mt * 16 + quad * 4 + rg;
        int cc = n0 + wn + nt * 16 + l16;
        size_t idx = (size_t)r * HID_ + cc;
        if (WRITE_MODE_SWITCH && md) ((float*)C)[idx] = acc[mt][nt][rg];
        else ((__hip_bfloat16*)C)[idx] = __float2bfloat16(acc[mt][nt][rg] * scl);
      }
}

__global__ __launch_bounds__(256) void gemm_bt128(const __hip_bfloat16* __restrict__ A,
                                                  const __hip_bfloat16* __restrict__ BT,
                                                  __hip_bfloat16* __restrict__ C, float scl) {
  gemm_body<0>(A, BT, (void*)C, 0, scl);
}

__global__ __launch_bounds__(256) void gemm_out(const __hip_bfloat16* __restrict__ A,
                                                const __hip_bfloat16* __restrict__ BT,
                                                void* __restrict__ C,
                                                const int* __restrict__ mode) {
  gemm_body<1>(A, BT, C, *mode, 1.0f);
}

// ---- q-projection GEMM with dual-bias epilogue: qw=(acc+rwb)*LSCL, qr=(acc+rrb)*LSCL ----
__global__ __launch_bounds__(256) void gemm_q(const __hip_bfloat16* __restrict__ A,
                                              const __hip_bfloat16* __restrict__ BT,
                                              const void* __restrict__ rwb,
                                              const void* __restrict__ rrb,
                                              __hip_bfloat16* __restrict__ qw,
                                              __hip_bfloat16* __restrict__ qr,
                                              const int* __restrict__ mode) {
  const int md = *mode;
  __shared__ __attribute__((aligned(16))) __hip_bfloat16 sA[128 * 32];
  __shared__ __attribute__((aligned(16))) __hip_bfloat16 sB[128 * 32];
  const int tid = threadIdx.x;
  const int lane = tid & 63;
  const int w = tid >> 6;
  const int quad = lane >> 4, l16 = lane & 15;
  const int m0 = blockIdx.x * 128;
  const int n0 = blockIdx.y * 128;
  const int wm = (w >> 1) * 64, wn = (w & 1) * 64;
  const f32x4 fz = {0.f, 0.f, 0.f, 0.f};

  f32x4 acc[4][4];
#pragma unroll
  for (int i = 0; i < 4; i++)
#pragma unroll
    for (int j = 0; j < 4; j++) acc[i][j] = fz;

  for (int kk = 0; kk < HID_ / 32; kk++) {
    const int k0 = kk * 32;
    __syncthreads();
#pragma unroll
    for (int t = 0; t < 2; t++) {
      int c = (w * 2 + t) * 64 + lane;
      int row = c >> 2;
      int cid = (c & 3) ^ (row & 3);
      async_copy16(A + (size_t)(m0 + row) * HID_ + k0 + cid * 8, (char*)sA + c * 16);
      async_copy16(BT + (size_t)(n0 + row) * HID_ + k0 + cid * 8, (char*)sB + c * 16);
    }
    __syncthreads();
    short8 af[4], bf[4];
#pragma unroll
    for (int mt = 0; mt < 4; mt++) {
      int r = wm + mt * 16 + l16;
      af[mt] = *(const short8*)((const char*)sA + r * 64 + ((quad ^ (r & 3)) * 16));
    }
#pragma unroll
    for (int nt = 0; nt < 4; nt++) {
      int r = wn + nt * 16 + l16;
      bf[nt] = *(const short8*)((const char*)sB + r * 64 + ((quad ^ (r & 3)) * 16));
    }
#pragma unroll
    for (int mt = 0; mt < 4; mt++)
#pragma unroll
      for (int nt = 0; nt < 4; nt++)
        acc[mt][nt] = __builtin_amdgcn_mfma_f32_16x16x32_bf16(af[mt], bf[nt], acc[mt][nt], 0, 0, 0);
  }
  float bw[4], br[4];
#pragma unroll
  for (int nt = 0; nt < 4; nt++) {
    int cc = n0 + wn + nt * 16 + l16;
    bw[nt] = ldin(rwb, cc, md);
    br[nt] = ldin(rrb, cc, md);
  }
#pragma unroll
  for (int mt = 0; mt < 4; mt++)
#pragma unroll
    for (int nt = 0; nt < 4; nt++)
#pragma unroll
      for (int rg = 0; rg < 4; rg++) {
        int r = m0 + wm + mt * 16 + quad * 4 + rg;
        int cc = n0 + wn + nt * 16 + l16;
        size_t idx = (size_t)r * HID_ + cc;
        float a = acc[mt][nt][rg];
        qw[idx] = __float2bfloat16((a + bw[nt]) * LSCL);
        qr[idx] = __float2bfloat16((a + br[nt]) * LSCL);
      }
}

// ---- dual GEMM: BT = contiguous [wkT; wvT]; K-half -> kpb (row-major), V-half -> vpt
// (transposed per-head layout [b][h][d][j]) via in-block LDS transpose epilogue. ----
__global__ __launch_bounds__(256) void gemm_dualv(const __hip_bfloat16* __restrict__ A,
                                                  const __hip_bfloat16* __restrict__ BT,
                                                  __hip_bfloat16* __restrict__ C0,
                                                  __hip_bfloat16* __restrict__ vpt) {
  __shared__ __attribute__((aligned(16))) __hip_bfloat16 sA[128 * 32];
  __shared__ __attribute__((aligned(16))) __hip_bfloat16 sB[128 * 32];
  __shared__ __attribute__((aligned(16))) short sT[128 * 136];  // 34816 B, pad row 272B
  const int tid = threadIdx.x;
  const int lane = tid & 63;
  const int w = tid >> 6;
  const int quad = lane >> 4, l16 = lane & 15;
  const int m0 = blockIdx.x * 128;
  const int n0 = blockIdx.y * 128;  // 0..1920
  const int wm = (w >> 1) * 64, wn = (w & 1) * 64;
  const f32x4 fz = {0.f, 0.f, 0.f, 0.f};

  f32x4 acc[4][4];
#pragma unroll
  for (int i = 0; i < 4; i++)
#pragma unroll
    for (int j = 0; j < 4; j++) acc[i][j] = fz;

  for (int kk = 0; kk < HID_ / 32; kk++) {
    const int k0 = kk * 32;
    __syncthreads();
#pragma unroll
    for (int t = 0; t < 2; t++) {
      int c = (w * 2 + t) * 64 + lane;
      int row = c >> 2;
      int cid = (c & 3) ^ (row & 3);
      async_copy16(A + (size_t)(m0 + row) * HID_ + k0 + cid * 8, (char*)sA + c * 16);
      async_copy16(BT + (size_t)(n0 + row) * HID_ + k0 + cid * 8, (char*)sB + c * 16);
    }
    __syncthreads();
    short8 af[4], bf[4];
#pragma unroll
    for (int mt = 0; mt < 4; mt++) {
      int r = wm + mt * 16 + l16;
      af[mt] = *(const short8*)((const char*)sA + r * 64 + ((quad ^ (r & 3)) * 16));
    }
#pragma unroll
    for (int nt = 0; nt < 4; nt++) {
      int r = wn + nt * 16 + l16;
      bf[nt] = *(const short8*)((const char*)sB + r * 64 + ((quad ^ (r & 3)) * 16));
    }
#pragma unroll
    for (int mt = 0; mt < 4; mt++)
#pragma unroll
      for (int nt = 0; nt < 4; nt++)
        acc[mt][nt] = __builtin_amdgcn_mfma_f32_16x16x32_bf16(af[mt], bf[nt], acc[mt][nt], 0, 0, 0);
  }
  if (n0 < HID_) {
    // K half: row-major write
#pragma unroll
    for (int mt = 0; mt < 4; mt++)
#pragma unroll
      for (int nt = 0; nt < 4; nt++)
#pragma unroll
        for (int rg = 0; rg < 4; rg++) {
          int r = m0 + wm + mt * 16 + quad * 4 + rg;
          int cc = n0 + wn + nt * 16 + l16;
          C0[(size_t)r * HID_ + cc] = __float2bfloat16(acc[mt][nt][rg]);
        }
  } else {
    // V half: transpose through sT -> vpt[((b*H+h)*D+d)*KL + j]
#pragma unroll
    for (int mt = 0; mt < 4; mt++)
#pragma unroll
      for (int nt = 0; nt < 4; nt++) {
        int r = wm + mt * 16 + quad * 4;   // local j base (rg 0..3 consecutive)
        int cc = wn + nt * 16 + l16;       // local col
        short4v pk;
#pragma unroll
        for (int rg = 0; rg < 4; rg++) pk[rg] = bfbits(acc[mt][nt][rg]);
        *(short4v*)&sT[cc * 136 + r] = pk;
      }
    __syncthreads();
    const int b = m0 >> 12;            // 4096 rows per batch
    const int j0g = m0 & (KL_ - 1);
    const int cg0 = n0 - HID_;
#pragma unroll
    for (int it = 0; it < 16; it++) {
      int cc = it * 8 + w * 2 + (lane >> 5);
      int jj = (lane & 31) * 4;
      int cg = cg0 + cc;
      int h = cg >> 6, d = cg & 63;
      short4v v = *(const short4v*)&sT[cc * 136 + jj];
      *(short4v*)(vpt + (((size_t)(b * H_ + h)) * D_ + d) * KL_ + j0g + jj) = v;
    }
  }
}

// ---------------- fused relative attention (bias-folded q: no cb/eb tables) ----------------
// grid 1024 flat (XCD-remapped), block 256 (4 waves). Logits in log2 units via pre-scaled
// q' = (q+rwb)*LSCL (S-path) and q'' = (q+rrb)*LSCL (T-path). K+rel+V^T DMA-staged between
// barriers A and B. sTP rows stride 304 B. 75 KB LDS -> 2 blocks/CU.
__global__ __launch_bounds__(256, 2) void attn_kernel(
    const __hip_bfloat16* __restrict__ qpw, const __hip_bfloat16* __restrict__ qpr,
    const __hip_bfloat16* __restrict__ kp, const __hip_bfloat16* __restrict__ vpt,
    const __hip_bfloat16* __restrict__ relp,
    const void* __restrict__ spanv, __hip_bfloat16* __restrict__ attn_out,
    const int* __restrict__ mode) {
  const int md = *mode;
  const int bid = blockIdx.x;
  const int bh = (bid & 7) + 8 * (bid >> 8);
  const int i0 = ((bid >> 3) & 31) * RT_;
  const int b = bh >> 4, h = bh & 15;

  const int tid = threadIdx.x;
  const int lane = tid & 63;
  const int w = tid >> 6;
  const int quad = lane >> 4, l16 = lane & 15;
  const int di = w * 16 + l16;        // this thread's softmax row (block-local)
  const int iRow = i0 + di;
  const f32x4 fz = {0.f, 0.f, 0.f, 0.f};

  __shared__ __attribute__((aligned(16))) __hip_bfloat16 sk[128 * 64];    // 16 KB K tile (q' staged here first)
  __shared__ __attribute__((aligned(16))) __hip_bfloat16 srel[192 * 64];  // 24 KB rel band
  __shared__ __attribute__((aligned(16))) __hip_bfloat16 svt[64 * 128];   // 16 KB V^T tile (q'' staged here first)
  __shared__ __attribute__((aligned(16))) short sTP[64 * 152];            // 19 KB T-band/P rows

  const int rb = di * 304;            // private row base (bytes), 16B-aligned

  const __hip_bfloat16* kbase = kp + (size_t)b * KL_ * HID_ + h * D_;
  const __hip_bfloat16* vtb = vpt + ((size_t)(b * H_ + h)) * D_ * KL_;
  const float sv = ldin(spanv, h, md);
  const float svQ = sv * (float)Q_;
  const int pb0 = Q_ - RT_ - i0;
  const int wof = (3 - w) * 16;       // this wave's T-band p-window offset
  const int ntiles = ((M_ + i0 + RT_ - 1) >> 7) + 1;

  // ---- stage q' (sk) and q'' (svt) once; read own-row B-fragments ----
  {
    const size_t qofs = ((size_t)(b * Q_ + i0)) * HID_ + h * D_;
    const __hip_bfloat16* qb = qpw + qofs;
    const __hip_bfloat16* qb2 = qpr + qofs;
#pragma unroll
    for (int t = 0; t < 2; t++) {
      int c = (w * 2 + t) * 64 + lane;
      int row = c >> 3;
      int cid = (c & 7) ^ (row & 7);
      async_copy16(qb + (size_t)row * HID_ + cid * 8, (char*)sk + c * 16);
      async_copy16(qb2 + (size_t)row * HID_ + cid * 8, (char*)svt + c * 16);
    }
  }
  __syncthreads();
  short8 qf[2], qrf[2];
#pragma unroll
  for (int ks = 0; ks < 2; ks++) {
    const int cid = ((ks * 4 + quad) ^ (di & 7)) * 16;
    qf[ks]  = *(const short8*)((const char*)sk  + di * 128 + cid);
    qrf[ks] = *(const short8*)((const char*)svt + di * 128 + cid);
  }

  float mrow = -3e38f, lrow = 0.f, dfrow = 0.f;
  f32x4 oacc[4];
#pragma unroll
  for (int dt = 0; dt < 4; dt++) oacc[dt] = fz;

  for (int kt = 0; kt < ntiles; kt++) {
    const int j0 = kt * WT_;
    const int pbase = pb0 + j0;

    __syncthreads();  // A: prior tile's LDS consumers done (and q-frag reads, tile 0)
    // ---- DMA staging: K (4), rel band (6), V^T (4) ----
#pragma unroll
    for (int t = 0; t < 4; t++) {
      int c = (w * 4 + t) * 64 + lane;
      int row = c >> 3;
      int cid = (c & 7) ^ (row & 7);
      async_copy16(kbase + (size_t)(j0 + row) * HID_ + cid * 8, (char*)sk + c * 16);
    }
#pragma unroll
    for (int t = 0; t < 6; t++) {
      int c = (w * 6 + t) * 64 + lane;
      int row = c >> 3;
      int cid = (c & 7) ^ (row & 7);
      int p = pbase + row; p = p < KL_ ? p : KL_ - 1;  // clamped rows feed only masked cols
      async_copy16(relp + (size_t)p * HID_ + h * D_ + cid * 8, (char*)srel + c * 16);
    }
#pragma unroll
    for (int t = 0; t < 4; t++) {
      int c = (w * 4 + t) * 64 + lane;
      int row = c >> 4;
      int cid = (c & 15) ^ (row & 15);
      async_copy16(vtb + (size_t)row * KL_ + j0 + cid * 8, (char*)svt + c * 16);
    }
    __syncthreads();  // B: DMA drained

    // ---- S^T[j][i] = K . q'^T ----
    f32x4 S[8];
#pragma unroll
    for (int mt = 0; mt < 8; mt++) S[mt] = fz;
#pragma unroll
    for (int mt = 0; mt < 8; mt++) {
      int r = mt * 16 + l16;
#pragma unroll
      for (int ks = 0; ks < 2; ks++) {
        short8 af = *(const short8*)((const char*)sk + r * 128 + (((ks * 4 + quad) ^ (r & 7)) * 16));
        S[mt] = __builtin_amdgcn_mfma_f32_16x16x32_bf16(af, qf[ks], S[mt], 0, 0, 0);
      }
    }

    // ---- T band (wave's 144-col window) = rel . q''^T, store into own sTP row ----
#pragma unroll
    for (int mt = 0; mt < 9; mt++) {
      f32x4 T = fz;
      int r = wof + mt * 16 + l16;
#pragma unroll
      for (int ks = 0; ks < 2; ks++) {
        short8 af = *(const short8*)((const char*)srel + r * 128 + (((ks * 4 + quad) ^ (r & 7)) * 16));
        T = __builtin_amdgcn_mfma_f32_16x16x32_bf16(af, qrf[ks], T, 0, 0, 0);
      }
      const int lo = mt * 16 + quad * 4;              // local band offset [0,144)
      short4v pk;
#pragma unroll
      for (int rg = 0; rg < 4; rg++) pk[rg] = bfbits(T[rg]);
      *(short4v*)((char*)sTP + rb + lo * 2) = pk;
    }

    // ---- gather with per-row shift (own row, in-order DS) ----
#pragma unroll
    for (int mt = 0; mt < 8; mt++)
#pragma unroll
      for (int rg = 0; rg < 4; rg++) {
        int tcl = 15 - l16 + mt * 16 + quad * 4 + rg;
        S[mt][rg] += __bfloat162float(*(const __hip_bfloat16*)((const char*)sTP + rb + tcl * 2));
      }

    // ---- logits (log2 units), causal mask only on tiles that can need it ----
    const bool causalT = (j0 + WT_ - 1 - i0) > M_;
    float mnew = mrow;
#pragma unroll
    for (int mt = 0; mt < 8; mt++) {
#pragma unroll
      for (int rg = 0; rg < 4; rg++) {
        float v = S[mt][rg];
        if (causalT) {
          int j = j0 + mt * 16 + quad * 4 + rg;
          if (j - iRow > M_) v = -1e30f;
        }
        S[mt][rg] = v;
        mnew = fmaxf(mnew, v);
      }
    }
    mnew = fmaxf(mnew, __shfl_xor(mnew, 16));
    mnew = fmaxf(mnew, __shfl_xor(mnew, 32));
    const float alpha = fexp2(mrow - mnew);
    mrow = mnew;
    lrow *= alpha; dfrow *= alpha;
    float aR[4];
#pragma unroll
    for (int rg = 0; rg < 4; rg++) aR[rg] = __shfl(alpha, quad * 4 + rg);
#pragma unroll
    for (int dt = 0; dt < 4; dt++)
#pragma unroll
      for (int rg = 0; rg < 4; rg++) oacc[dt][rg] *= aR[rg];

    // ---- P = exp2(S-m); span deficit only on tiles overlapping the ramp ----
    const bool maskT = (j0 + WT_ > M_) && ((float)j0 < (float)M_ + 33.f - svQ);
#pragma unroll
    for (int mt = 0; mt < 8; mt++) {
      short4v pk;
#pragma unroll
      for (int rg = 0; rg < 4; rg++) {
        float pv = fexp2(S[mt][rg] - mrow);
        lrow += pv;
        float pm = pv;
        if (maskT) {
          int j = j0 + mt * 16 + quad * 4 + rg;
          if (j >= M_) {
            float t0 = (float)(j - M_) + svQ;
            float mk = fminf(fmaxf(t0 * (1.0f / 33.0f), 0.f), 1.f);
            pm = pv * mk;
            dfrow += pv - pm;
          }
        }
        pk[rg] = bfbits(pm);
      }
      *(short4v*)((char*)sTP + rb + (mt * 16 + quad * 4) * 2) = pk;
    }

    // ---- PV: A = P (own rows, b128 from sTP), B = V^T rows from svt ----
#pragma unroll
    for (int ks = 0; ks < 4; ks++) {
      short8 af = *(const short8*)((const char*)sTP + rb + ks * 64 + quad * 16);
#pragma unroll
      for (int dt = 0; dt < 4; dt++) {
        int r = dt * 16 + l16;
        short8 bfv = *(const short8*)((const char*)svt + r * 256 + (((ks * 4 + quad) ^ (r & 15)) * 16));
        oacc[dt] = __builtin_amdgcn_mfma_f32_16x16x32_bf16(af, bfv, oacc[dt], 0, 0, 0);
      }
    }
  }

  // ---- epilogue: lm = lr - deficit ----
  lrow += __shfl_xor(lrow, 16);  lrow += __shfl_xor(lrow, 32);
  dfrow += __shfl_xor(dfrow, 16); dfrow += __shfl_xor(dfrow, 32);
  float lr4[4], df4[4];
#pragma unroll
  for (int rg = 0; rg < 4; rg++) {
    lr4[rg] = __shfl(lrow, quad * 4 + rg);
    df4[rg] = __shfl(dfrow, quad * 4 + rg);
  }
#pragma unroll
  for (int dt = 0; dt < 4; dt++)
#pragma unroll
    for (int rg = 0; rg < 4; rg++) {
      int i = i0 + w * 16 + quad * 4 + rg;
      float denom = (lr4[rg] - df4[rg]) + 1e-8f * lr4[rg];
      float ov = oacc[dt][rg] / denom;
      attn_out[((size_t)(b * Q_ + i)) * HID_ + h * D_ + dt * 16 + l16] = __float2bfloat16(ov);
    }
}

// ---------------- launcher ----------------
extern "C" void kernel_launch(void* const* d_in, const int* in_sizes, int n_in,
                              void* d_out, int out_size, void* d_ws, size_t ws_size,
                              hipStream_t stream) {
  const void* query  = d_in[0];
  const void* memory = d_in[1];
  const void* Wq = d_in[2];
  const void* Wk = d_in[3];
  const void* Wv = d_in[4];
  const void* Wo = d_in[5];
  const void* Wr = d_in[6];
  const void* gmem = d_in[7];
  const void* bmem = d_in[8];
  const void* gq = d_in[9];
  const void* bq = d_in[10];
  const void* rwb = d_in[11];
  const void* rrb = d_in[12];
  const void* spanv = d_in[13];

  char* ws = (char*)d_ws;
  size_t off = 0;
  auto alloc = [&](size_t bytes) -> char* {
    char* p = ws + off;
    off += (bytes + 255) & ~(size_t)255;
    return p;
  };
  int* flag = (int*)alloc(256);
  const size_t SZ_W = (size_t)HID_ * HID_ * 2;
  __hip_bfloat16* wqT = (__hip_bfloat16*)alloc(SZ_W);
  __hip_bfloat16* wkT = (__hip_bfloat16*)alloc(SZ_W);   // contiguous with wvT (SZ_W is 256B-aligned)
  __hip_bfloat16* wvT = (__hip_bfloat16*)alloc(SZ_W);
  __hip_bfloat16* wrT = (__hip_bfloat16*)alloc(SZ_W);
  __hip_bfloat16* woT = (__hip_bfloat16*)alloc(SZ_W);
  __hip_bfloat16* kvln = (__hip_bfloat16*)alloc((size_t)B_ * KL_ * HID_ * 2);
  __hip_bfloat16* qln  = (__hip_bfloat16*)alloc((size_t)B_ * Q_ * HID_ * 2);
  __hip_bfloat16* pe   = (__hip_bfloat16*)alloc((size_t)KL_ * HID_ * 2);
  __hip_bfloat16* qpw  = (__hip_bfloat16*)alloc((size_t)B_ * Q_ * HID_ * 2);
  __hip_bfloat16* qpr  = (__hip_bfloat16*)alloc((size_t)B_ * Q_ * HID_ * 2);
  __hip_bfloat16* kpb  = (__hip_bfloat16*)alloc((size_t)B_ * KL_ * HID_ * 2);
  __hip_bfloat16* vptb = (__hip_bfloat16*)alloc((size_t)B_ * KL_ * HID_ * 2);  // V, transposed per-head
  __hip_bfloat16* relp = (__hip_bfloat16*)alloc((size_t)KL_ * HID_ * 2);
  __hip_bfloat16* aout = (__hip_bfloat16*)alloc((size_t)B_ * Q_ * HID_ * 2);

  dim3 tb(256);
  detect_kernel<<<dim3(1), tb, 0, stream>>>((const unsigned int*)query, flag);

  wtpe_kernel<<<dim3(16, 16, 21), tb, 0, stream>>>(Wq, Wk, Wv, Wr, Wo,
                                                   wqT, wkT, wvT, wrT, woT, pe, flag);

  ln_kernel<<<dim3(B_ * KL_ + B_ * Q_), tb, 0, stream>>>(memory, query, gmem, bmem, gq, bq,
                                                         kvln, qln, flag);

  gemm_q<<<dim3(B_ * Q_ / 128, HID_ / 128), tb, 0, stream>>>(qln, wqT, rwb, rrb, qpw, qpr, flag);
  gemm_dualv<<<dim3(B_ * KL_ / 128, 2 * HID_ / 128), tb, 0, stream>>>(kvln, wkT, kpb, vptb);
  gemm_bt128<<<dim3(KL_ / 128, HID_ / 128), tb, 0, stream>>>(pe, wrT, relp, 1.0f);

  attn_kernel<<<dim3((Q_ / RT_) * H_ * B_), tb, 0, stream>>>(qpw, qpr, kpb, vptb, relp, spanv, aout, flag);

  gemm_out<<<dim3(B_ * Q_ / 128, HID_ / 128), tb, 0, stream>>>(aout, woT, d_out, flag);

  (void)in_sizes; (void)n_in; (void)out_size; (void)ws_size;
}